// Round 9
// baseline (1264.961 us; speedup 1.0000x reference)
//
#include <hip/hip_runtime.h>
#include <hip/hip_bf16.h>
#include <stdint.h>

#define NN 4096
#define DD 256
#define NL 3
typedef unsigned int uint;
typedef unsigned short ushort_t;

typedef float f32x4 __attribute__((ext_vector_type(4)));
typedef short bf16x8 __attribute__((ext_vector_type(8)));

struct Ptrs4 { const float* p0; const float* p1; const float* p2; const float* p3; };
__device__ __forceinline__ const float* sel(const Ptrs4& p, int b) {
    return b == 0 ? p.p0 : b == 1 ? p.p1 : b == 2 ? p.p2 : p.p3;
}

// packed bf16 pair (RNE), low half = a, high half = b
__device__ __forceinline__ uint pkbf2(float a, float b) {
    __hip_bfloat162 t = __float22bfloat162_rn(float2{a, b});
    union { __hip_bfloat162 h; uint u; } c; c.h = t; return c.u;
}
// exact 3-way split of a pair: x = h + m + l + r, |r| <= ~2^-27 |x|
__device__ __forceinline__ void split3_pk(float a, float b, uint& h, uint& m, uint& l) {
    h = pkbf2(a, b);
    float ha = __uint_as_float(h << 16), hb = __uint_as_float(h & 0xFFFF0000u);
    float ra = a - ha, rb = b - hb;
    m = pkbf2(ra, rb);
    float ma = __uint_as_float(m << 16), mb = __uint_as_float(m & 0xFFFF0000u);
    l = pkbf2(ra - ma, rb - mb);
}

// async global->LDS; LDS dest = wave-uniform base + lane*size; global src per-lane
typedef __attribute__((address_space(3))) uint lds_u32;
typedef __attribute__((address_space(1))) const uint glb_u32;
__device__ __forceinline__ void gload16(void* l, const void* g) {
    __builtin_amdgcn_global_load_lds((glb_u32*)g, (lds_u32*)l, 16, 0, 0);
}
__device__ __forceinline__ void gload4(void* l, const void* g) {
    __builtin_amdgcn_global_load_lds((glb_u32*)g, (lds_u32*)l, 4, 0, 0);
}

// ---------------------------------------------------------------------------
// fp32 GEMM (R6 reg-prefetch + R18 LDS double-buffer: ONE barrier per tile).
// Out = act(X @ W + b). Per-output fmaf chain unchanged => bit-exact.
// MODE 0: elu; MODE 1: elu + colsum (fallback); MODE 2: linear + BN stats;
// MODE 3: elu + colsum, bf16 3-split out in Hs[lvl][d/8][n][8] layout.
// ---------------------------------------------------------------------------
template<int MODE>
__global__ __launch_bounds__(256, 4)
void gemm_small(const float* __restrict__ Xin, Ptrs4 Wp, Ptrs4 bp,
                float* __restrict__ Out, float* __restrict__ cs, float* __restrict__ csq,
                ushort_t* __restrict__ Hso)
{
    const int b = blockIdx.z;
    const float* Wb = sel(Wp, b);
    const float* bb = sel(bp, b);
    const float* X = Xin + (size_t)b * NN * DD;
    float* O = Out + (size_t)b * NN * DD;
    ushort_t* HsO = Hso + (size_t)b * 3 * (size_t)DD * NN;
    const int row0 = blockIdx.y * 128, col0 = blockIdx.x * 64;
    const int tid = threadIdx.x;
    __shared__ float Asm[2][16][132];   // 16.9 KB
    __shared__ float Bsm[2][16][68];    // 8.7 KB
    const int tr = (tid >> 4) << 3, tc = (tid & 15) << 2;
    const int m = tid & 127, kk = (tid >> 7) << 3;
    const int bk = tid >> 4, bn = (tid & 15) << 2;
    const float* aSrc = X + (size_t)(row0 + m) * DD + kk;
    const float* bSrc = Wb + (size_t)bk * DD + col0 + bn;

    float acc[8][4] = {};
    float4 pa0 = *(const float4*)(aSrc);
    float4 pa1 = *(const float4*)(aSrc + 4);
    float4 pb  = *(const float4*)(bSrc);
    for (int t = 0; t < DD / 16; ++t) {
        const int cur = t & 1;
        Asm[cur][kk+0][m]=pa0.x; Asm[cur][kk+1][m]=pa0.y;
        Asm[cur][kk+2][m]=pa0.z; Asm[cur][kk+3][m]=pa0.w;
        Asm[cur][kk+4][m]=pa1.x; Asm[cur][kk+5][m]=pa1.y;
        Asm[cur][kk+6][m]=pa1.z; Asm[cur][kk+7][m]=pa1.w;
        *(float4*)&Bsm[cur][bk][bn] = pb;
        __syncthreads();
        if (t < DD / 16 - 1) {
            const int k0 = (t + 1) * 16;
            pa0 = *(const float4*)(aSrc + k0);
            pa1 = *(const float4*)(aSrc + k0 + 4);
            pb  = *(const float4*)(bSrc + (size_t)k0 * DD);
        }
        #pragma unroll
        for (int k = 0; k < 16; ++k) {
            float a[8], bv[4];
            *(float4*)&a[0] = *(const float4*)&Asm[cur][k][tr];
            *(float4*)&a[4] = *(const float4*)&Asm[cur][k][tr + 4];
            *(float4*)&bv[0] = *(const float4*)&Bsm[cur][k][tc];
            #pragma unroll
            for (int i = 0; i < 8; ++i)
                #pragma unroll
                for (int j = 0; j < 4; ++j)
                    acc[i][j] = fmaf(a[i], bv[j], acc[i][j]);
        }
    }
    float bias4[4];
    *(float4*)bias4 = *(const float4*)(bb + col0 + tc);
    float s4[4] = {0.f,0.f,0.f,0.f}, q4[4] = {0.f,0.f,0.f,0.f};
    // MODE 3 split-store geometry: d = col0+tc (mult of 4), layout [lvl][d>>3][n][8]
    const int dph = col0 + tc;
    const size_t sb3 = (size_t)(dph >> 3) * (NN * 8) + (dph & 4);
    #pragma unroll
    for (int i = 0; i < 8; ++i) {
        float ov[4];
        #pragma unroll
        for (int j = 0; j < 4; ++j) {
            float v = acc[i][j] + bias4[j];
            if (MODE == 0 || MODE == 1 || MODE == 3) v = (v > 0.f) ? v : (expf(v) - 1.f);
            ov[j] = v;
            if (MODE == 1 || MODE == 3) s4[j] += v;
            if (MODE == 2) { s4[j] += v; q4[j] += v * v; }
        }
        if (MODE == 3) {
            uint2 vh, vm, vl;
            split3_pk(ov[0], ov[1], vh.x, vm.x, vl.x);
            split3_pk(ov[2], ov[3], vh.y, vm.y, vl.y);
            size_t off = sb3 + (size_t)(row0 + tr + i) * 8;
            *(uint2*)(HsO + off) = vh;
            *(uint2*)(HsO + (size_t)DD * NN + off) = vm;
            *(uint2*)(HsO + (size_t)2 * DD * NN + off) = vl;
        } else {
            float4 o; o.x = ov[0]; o.y = ov[1]; o.z = ov[2]; o.w = ov[3];
            *(float4*)(O + (size_t)(row0 + tr + i) * DD + col0 + tc) = o;
        }
    }
    if (MODE == 1 || MODE == 2 || MODE == 3) {
        float* scrS = &Asm[0][0][0];   // scratch, stride 132 (post-loop, barrier-protected)
        float* scrQ = &Bsm[0][0][0];   // stride 68
        __syncthreads();
        const int rg = tid >> 4;
        #pragma unroll
        for (int j = 0; j < 4; ++j) {
            scrS[rg * 132 + tc + j] = s4[j];
            if (MODE == 2) scrQ[rg * 68 + tc + j] = q4[j];
        }
        __syncthreads();
        if (tid < 64) {
            float s = 0.f, q = 0.f;
            #pragma unroll
            for (int r = 0; r < 16; ++r) { s += scrS[r * 132 + tid]; if (MODE == 2) q += scrQ[r * 68 + tid]; }
            atomicAdd(&cs[b * DD + col0 + tid], s);
            if (MODE == 2) atomicAdd(&csq[b * DD + col0 + tid], q);
        }
    }
}

// threshold per branch: t = ||colsum||^2 / N^2
__global__ void thresh_k(const float* __restrict__ cs, float* __restrict__ tvals)
{
    const int b = blockIdx.x, t = threadIdx.x;
    __shared__ float red[256];
    float v = cs[b * DD + t];
    red[t] = v * v;
    __syncthreads();
    for (int s = 128; s > 0; s >>= 1) { if (t < s) red[t] += red[t + s]; __syncthreads(); }
    if (t == 0) tvals[b] = red[0] * (1.0f / 16777216.0f);
}

// ---------------------------------------------------------------------------
// transpose + exact 3-split: X[b][n][d] fp32 -> S{h,m,l}[b][d][j=n] bf16.
// ---------------------------------------------------------------------------
__global__ __launch_bounds__(256)
void tsplit_x(const float* __restrict__ Xin, ushort_t* __restrict__ Sh,
              ushort_t* __restrict__ Sm, ushort_t* __restrict__ Sl)
{
    const int b = blockIdx.z;
    const int n0 = blockIdx.x * 64, d0 = blockIdx.y * 64;
    const float* X = Xin + (size_t)b * NN * DD;
    __shared__ float ls[64][65];
    const int tid = threadIdx.x;
    #pragma unroll
    for (int i = 0; i < 4; ++i) {
        int u = (i << 8) + tid;
        int r = u >> 4, c4 = (u & 15) << 2;   // r = n-row, c4 = d offset
        float4 v = *(const float4*)(X + (size_t)(n0 + r) * DD + d0 + c4);
        ls[r][c4] = v.x; ls[r][c4+1] = v.y; ls[r][c4+2] = v.z; ls[r][c4+3] = v.w;
    }
    __syncthreads();
    const int d = tid >> 2, seg = (tid & 3) << 4;   // 16 n-values per thread
    uint ph[8], pm[8], pl[8];
    #pragma unroll
    for (int jj = 0; jj < 8; ++jj) {
        float a = ls[seg + 2 * jj][d];
        float c = ls[seg + 2 * jj + 1][d];
        split3_pk(a, c, ph[jj], pm[jj], pl[jj]);
    }
    size_t idx = ((size_t)(b * DD + d0 + d)) * NN + n0 + seg;   // ushort units
    *(uint4*)(Sh + idx)     = *(uint4*)&ph[0];
    *(uint4*)(Sh + idx + 8) = *(uint4*)&ph[4];
    *(uint4*)(Sm + idx)     = *(uint4*)&pm[0];
    *(uint4*)(Sm + idx + 8) = *(uint4*)&pm[4];
    *(uint4*)(Sl + idx)     = *(uint4*)&pl[0];
    *(uint4*)(Sl + idx + 8) = *(uint4*)&pl[4];
}

// ---------------------------------------------------------------------------
// adj v1 (fallback, proven): fp32 staging + in-tile split.
// ---------------------------------------------------------------------------
__global__ __launch_bounds__(256, 3)
void adj_mfma_s(const float* __restrict__ H, const float* __restrict__ tvals,
                uint8_t* __restrict__ mask)
{
    int t = blockIdx.x;
    int by = 0, rem = 32;
    while (t >= rem) { t -= rem; rem--; by++; }
    const int bx = by + t;
    const int b = blockIdx.z;
    const int row0 = by * 128, col0 = bx * 128;
    const int tid = threadIdx.x;
    const int wave = tid >> 6, ln = tid & 15, quad = (tid >> 4) & 3;
    const int wrow = wave >> 1, wcol = wave & 1;
    const float* Hb = H + (size_t)b * NN * DD;
    uint8_t* Mb = mask + (size_t)b * NN * (NN / 8);
    __shared__ ushort_t hs[2][3][128][34];

    f32x4 acc[4][4] = {};
    for (int k0 = 0; k0 < DD; k0 += 32) {
        #pragma unroll
        for (int i = 0; i < 8; ++i) {
            int f = (i << 8) + tid;
            int sr = f >> 3;
            int side = sr >> 7, r = sr & 127, part = f & 7;
            int grow = (side ? col0 : row0) + r;
            float4 v = *(const float4*)(Hb + (size_t)grow * DD + k0 + part * 4);
            uint h0, m0, l0, h1, m1, l1;
            split3_pk(v.x, v.y, h0, m0, l0);
            split3_pk(v.z, v.w, h1, m1, l1);
            uint2 ph; ph.x = h0; ph.y = h1;
            uint2 pm; pm.x = m0; pm.y = m1;
            uint2 pl; pl.x = l0; pl.y = l1;
            *(uint2*)&hs[side][0][r][part * 4] = ph;
            *(uint2*)&hs[side][1][r][part * 4] = pm;
            *(uint2*)&hs[side][2][r][part * 4] = pl;
        }
        __syncthreads();
        bf16x8 af[4][3];
        #pragma unroll
        for (int mt = 0; mt < 4; ++mt)
            #pragma unroll
            for (int lvl = 0; lvl < 3; ++lvl)
                af[mt][lvl] = *(const bf16x8*)&hs[0][lvl][wrow * 64 + mt * 16 + ln][quad * 8];
        #pragma unroll
        for (int nt = 0; nt < 4; ++nt) {
            int n = wcol * 64 + nt * 16 + ln;
            bf16x8 bh = *(const bf16x8*)&hs[1][0][n][quad * 8];
            bf16x8 bm = *(const bf16x8*)&hs[1][1][n][quad * 8];
            bf16x8 bl = *(const bf16x8*)&hs[1][2][n][quad * 8];
            #pragma unroll
            for (int mt = 0; mt < 4; ++mt) {
                f32x4 a = acc[mt][nt];
                a = __builtin_amdgcn_mfma_f32_16x16x32_bf16(af[mt][0], bh, a, 0, 0, 0);
                a = __builtin_amdgcn_mfma_f32_16x16x32_bf16(af[mt][0], bm, a, 0, 0, 0);
                a = __builtin_amdgcn_mfma_f32_16x16x32_bf16(af[mt][1], bh, a, 0, 0, 0);
                a = __builtin_amdgcn_mfma_f32_16x16x32_bf16(af[mt][0], bl, a, 0, 0, 0);
                a = __builtin_amdgcn_mfma_f32_16x16x32_bf16(af[mt][2], bh, a, 0, 0, 0);
                a = __builtin_amdgcn_mfma_f32_16x16x32_bf16(af[mt][1], bm, a, 0, 0, 0);
                acc[mt][nt] = a;
            }
        }
        __syncthreads();
    }
    const float t2 = tvals[b];
    #pragma unroll
    for (int mt = 0; mt < 4; ++mt)
        #pragma unroll
        for (int nt = 0; nt < 4; ++nt) {
            bool p0 = acc[mt][nt][0] > t2, p1 = acc[mt][nt][1] > t2;
            bool p2 = acc[mt][nt][2] > t2, p3 = acc[mt][nt][3] > t2;
            unsigned long long bal[4];
            bal[0] = __ballot(p0); bal[1] = __ballot(p1);
            bal[2] = __ballot(p2); bal[3] = __ballot(p3);
            if ((tid & 63) < 16) {
                int q = ln >> 2, rsel = ln & 3;
                unsigned long long bv = rsel == 0 ? bal[0] : rsel == 1 ? bal[1]
                                       : rsel == 2 ? bal[2] : bal[3];
                ushort_t u16 = (ushort_t)((bv >> (q * 16)) & 0xFFFFull);
                int row = row0 + wrow * 64 + mt * 16 + ln;
                int colb = (col0 + wcol * 64 + nt * 16) >> 3;
                *(ushort_t*)(Mb + (size_t)row * (NN / 8) + colb) = u16;
            }
            uint nib = (p0 ? 1u : 0u) | (p1 ? 2u : 0u) | (p2 ? 4u : 0u) | (p3 ? 8u : 0u);
            uint other = (uint)__shfl_xor((int)nib, 16);
            if ((quad & 1) == 0) {
                uint byt = nib | (other << 4);
                int rowm = col0 + wcol * 64 + nt * 16 + ln;
                int colbm = ((row0 + wrow * 64 + mt * 16) >> 3) + (quad >> 1);
                Mb[(size_t)rowm * (NN / 8) + colbm] = (uint8_t)byt;
            }
        }
}

// ---------------------------------------------------------------------------
// adj v2 (fast path): pure bf16 MFMA from precomputed splits. (R0-proven DMA
// version — R17's register prefetch reverted: VGPR cap at (256,3) defeated it.)
// ---------------------------------------------------------------------------
__global__ __launch_bounds__(256, 3)
void adj_mfma_v2(const ushort_t* __restrict__ Hs, const float* __restrict__ tvals,
                 uint8_t* __restrict__ mask)
{
    int t = blockIdx.x;
    int by = 0, rem = 32;
    while (t >= rem) { t -= rem; rem--; by++; }
    const int bx = by + t;
    const int b = blockIdx.z;
    const int row0 = by * 128, col0 = bx * 128;
    const int tid = threadIdx.x;
    const int wave = tid >> 6, ln = tid & 15, quad = (tid >> 4) & 3;
    const int wrow = wave >> 1, wcol = wave & 1;
    const ushort_t* Hb = Hs + (size_t)b * 3 * (size_t)DD * NN;
    uint8_t* Mb = mask + (size_t)b * NN * (NN / 8);
    __shared__ ushort_t hs2[6][4][128][8];   // 48 KB, linear (DMA-friendly)

    const int grow = tid & 127;
    const int qb = tid >> 7;                  // 0/1
    const size_t var0 = (size_t)qb * (NN * 8) + (size_t)(row0 + grow) * 8;
    const size_t var1 = (size_t)qb * (NN * 8) + (size_t)(col0 + grow) * 8;

    f32x4 acc[4][4] = {};
    for (int kb0 = 0; kb0 < DD / 8; kb0 += 4) {     // 32 k per iter
        #pragma unroll
        for (int c = 0; c < 12; ++c) {
            const int sl = c >> 1, part = c & 1;    // sl = side*3+lvl
            const int side = sl / 3, lvl = sl % 3;
            const ushort_t* g = Hb + (size_t)lvl * DD * NN
                                   + (size_t)(kb0 + part * 2) * (NN * 8)
                                   + (side ? var1 : var0);
            char* l = (char*)&hs2[0][0][0][0] + (((sl * 8 + part * 4 + wave)) << 10);
            gload16(l, g);
        }
        __syncthreads();
        bf16x8 af[4][3];
        #pragma unroll
        for (int mt = 0; mt < 4; ++mt)
            #pragma unroll
            for (int lvl = 0; lvl < 3; ++lvl)
                af[mt][lvl] = *(const bf16x8*)&hs2[lvl][quad][wrow * 64 + mt * 16 + ln][0];
        #pragma unroll
        for (int nt = 0; nt < 4; ++nt) {
            const int n = wcol * 64 + nt * 16 + ln;
            bf16x8 bh = *(const bf16x8*)&hs2[3][quad][n][0];
            bf16x8 bm = *(const bf16x8*)&hs2[4][quad][n][0];
            bf16x8 bl = *(const bf16x8*)&hs2[5][quad][n][0];
            #pragma unroll
            for (int mt = 0; mt < 4; ++mt) {
                f32x4 a = acc[mt][nt];
                a = __builtin_amdgcn_mfma_f32_16x16x32_bf16(af[mt][0], bh, a, 0, 0, 0);
                a = __builtin_amdgcn_mfma_f32_16x16x32_bf16(af[mt][0], bm, a, 0, 0, 0);
                a = __builtin_amdgcn_mfma_f32_16x16x32_bf16(af[mt][1], bh, a, 0, 0, 0);
                a = __builtin_amdgcn_mfma_f32_16x16x32_bf16(af[mt][0], bl, a, 0, 0, 0);
                a = __builtin_amdgcn_mfma_f32_16x16x32_bf16(af[mt][2], bh, a, 0, 0, 0);
                a = __builtin_amdgcn_mfma_f32_16x16x32_bf16(af[mt][1], bm, a, 0, 0, 0);
                acc[mt][nt] = a;
            }
        }
        __syncthreads();
    }
    const float t2 = tvals[b];
    #pragma unroll
    for (int mt = 0; mt < 4; ++mt)
        #pragma unroll
        for (int nt = 0; nt < 4; ++nt) {
            bool p0 = acc[mt][nt][0] > t2, p1 = acc[mt][nt][1] > t2;
            bool p2 = acc[mt][nt][2] > t2, p3 = acc[mt][nt][3] > t2;
            unsigned long long bal[4];
            bal[0] = __ballot(p0); bal[1] = __ballot(p1);
            bal[2] = __ballot(p2); bal[3] = __ballot(p3);
            if ((tid & 63) < 16) {
                int q = ln >> 2, rsel = ln & 3;
                unsigned long long bv = rsel == 0 ? bal[0] : rsel == 1 ? bal[1]
                                       : rsel == 2 ? bal[2] : bal[3];
                ushort_t u16 = (ushort_t)((bv >> (q * 16)) & 0xFFFFull);
                int row = row0 + wrow * 64 + mt * 16 + ln;
                int colb = (col0 + wcol * 64 + nt * 16) >> 3;
                *(ushort_t*)(Mb + (size_t)row * (NN / 8) + colb) = u16;
            }
            uint nib = (p0 ? 1u : 0u) | (p1 ? 2u : 0u) | (p2 ? 4u : 0u) | (p3 ? 8u : 0u);
            uint other = (uint)__shfl_xor((int)nib, 16);
            if ((quad & 1) == 0) {
                uint byt = nib | (other << 4);
                int rowm = col0 + wcol * 64 + nt * 16 + ln;
                int colbm = ((row0 + wrow * 64 + mt * 16) >> 3) + (quad >> 1);
                Mb[(size_t)rowm * (NN / 8) + colbm] = (uint8_t)byt;
            }
        }
}

// ---------------------------------------------------------------------------
// X' = X + M @ X via MFMA, IN-PLACE into X.  (R3 DMA dbuf + XOR swz +
// R7-proven 256x16B LDS decode LUT.)
// ---------------------------------------------------------------------------
__global__ __launch_bounds__(256)
void masked_mfma(float* __restrict__ Xio, const ushort_t* __restrict__ Sh,
                 const ushort_t* __restrict__ Sm, const ushort_t* __restrict__ Sl,
                 const uint8_t* __restrict__ mask)
{
    const int b = blockIdx.z;
    const int row0 = blockIdx.y * 128, col0 = blockIdx.x * 64;
    const int tid = threadIdx.x;
    const int wave = tid >> 6, ln = tid & 15, quad = (tid >> 4) & 3;
    const int wrow = wave >> 1, wcol = wave & 1;
    float* X = Xio + (size_t)b * NN * DD;
    const size_t sb = (size_t)b * DD * NN;
    const ushort_t* Ss[3] = { Sh + sb, Sm + sb, Sl + sb };
    const uint* Mw = (const uint*)(mask + (size_t)b * NN * (NN / 8));
    __shared__ ushort_t bt2[2][3][2][64][32];   // [buf][lvl][khalf][col][32j], 48 KB
    __shared__ uint msk2[2][2][128];            // [buf][khalf][row], 2 KB
    __shared__ uint lut[256][4];                // byte -> bf16x8 mask row, 4 KB

    // build decode LUT (bit-identical to the arithmetic decode)
    #pragma unroll
    for (int p = 0; p < 4; ++p)
        lut[tid][p] = (((tid >> (2 * p)) & 1u) ? 0x3F80u : 0u) |
                      (((tid >> (2 * p + 1)) & 1u) ? 0x3F800000u : 0u);

    const int c = tid >> 2;
    const int qp = (tid & 3) ^ ((tid >> 3) & 3);
    const size_t goff = (size_t)(col0 + c) * NN + (size_t)qp * 8;  // + j
    const size_t mrow = (size_t)(row0 + (tid & 127)) * 128;        // uint units

    f32x4 acc[4][2] = {};

    #define STAGE(buf, t)                                                         \
        {                                                                         \
            const size_t j_ = (size_t)(t) * 64;                                   \
            _Pragma("unroll")                                                     \
            for (int lvl = 0; lvl < 3; ++lvl) {                                   \
                gload16((char*)&bt2[buf][lvl][0][0][0] + (wave << 10),            \
                        Ss[lvl] + goff + j_);                                     \
                gload16((char*)&bt2[buf][lvl][1][0][0] + (wave << 10),            \
                        Ss[lvl] + goff + j_ + 32);                                \
            }                                                                     \
            if (tid < 128) {                                                      \
                gload4((char*)&msk2[buf][0][0] + (wave << 8), Mw + mrow + 2*(t)); \
                gload4((char*)&msk2[buf][1][0] + (wave << 8), Mw + mrow + 2*(t)+1);\
            }                                                                     \
        }

    STAGE(0, 0);
    __syncthreads();   // also publishes the LUT

    for (int t = 0; t < NN / 64; ++t) {
        const int cur = t & 1;
        if (t < NN / 64 - 1) STAGE(cur ^ 1, t + 1);
        #pragma unroll
        for (int kk = 0; kk < 2; ++kk) {
            bf16x8 afr[4];
            #pragma unroll
            for (int mt = 0; mt < 4; ++mt) {
                uint w = msk2[cur][kk][wrow * 64 + mt * 16 + ln];
                uint byte = (w >> (quad * 8)) & 0xFFu;
                afr[mt] = *(const bf16x8*)&lut[byte][0];
            }
            #pragma unroll
            for (int nt = 0; nt < 2; ++nt) {
                const int n = wcol * 32 + nt * 16 + ln;
                const int slot = (quad ^ ((n >> 1) & 3)) * 8;
                bf16x8 bh = *(const bf16x8*)&bt2[cur][0][kk][n][slot];
                bf16x8 bm = *(const bf16x8*)&bt2[cur][1][kk][n][slot];
                bf16x8 bl = *(const bf16x8*)&bt2[cur][2][kk][n][slot];
                #pragma unroll
                for (int mt = 0; mt < 4; ++mt) {
                    f32x4 a = acc[mt][nt];
                    a = __builtin_amdgcn_mfma_f32_16x16x32_bf16(afr[mt], bh, a, 0, 0, 0);
                    a = __builtin_amdgcn_mfma_f32_16x16x32_bf16(afr[mt], bm, a, 0, 0, 0);
                    a = __builtin_amdgcn_mfma_f32_16x16x32_bf16(afr[mt], bl, a, 0, 0, 0);
                    acc[mt][nt] = a;
                }
            }
        }
        __syncthreads();
    }
    #undef STAGE
    #pragma unroll
    for (int mt = 0; mt < 4; ++mt)
        #pragma unroll
        for (int nt = 0; nt < 2; ++nt)
            #pragma unroll
            for (int r = 0; r < 4; ++r) {
                int row = row0 + wrow * 64 + mt * 16 + quad * 4 + r;
                int col = col0 + wcol * 32 + nt * 16 + ln;
                size_t idx = (size_t)row * DD + col;
                X[idx] = X[idx] + acc[mt][nt][r];
            }
}

// ---------------------------------------------------------------------------
// X = relu(bn(G)) @ W + bias;  acc (+)= X.  (reg prefetch + LDS dbuf; BN at
// ds_write with identical op sequence => bit-exact.)
// ---------------------------------------------------------------------------
__global__ __launch_bounds__(256, 4)
void gemm_bnrelu(const float* __restrict__ G, Ptrs4 Wp, Ptrs4 bp, Ptrs4 gbp,
                 const float* __restrict__ bns, const float* __restrict__ bnq,
                 float* __restrict__ Xout, float* __restrict__ accb, int first)
{
    const int b = blockIdx.z;
    const float* Wb = sel(Wp, b);
    const float* bb = sel(bp, b);
    const float* gb = sel(gbp, b);
    const float* Gb = G + (size_t)b * NN * DD;
    float* O = Xout + (size_t)b * NN * DD;
    float* Ab = accb + (size_t)b * NN * DD;
    const int row0 = blockIdx.y * 128, col0 = blockIdx.x * 64;
    const int tid = threadIdx.x;
    __shared__ float Asm[2][16][132];
    __shared__ float Bsm[2][16][68];
    __shared__ float scs[DD], shs[DD];
    {
        float mu = bns[b * DD + tid] * (1.0f / NN);
        float ms = bnq[b * DD + tid] * (1.0f / NN);
        float var = ms - mu * mu;
        float sc = gb[tid] / sqrtf(var + 1e-5f);
        scs[tid] = sc;
        shs[tid] = gb[DD + tid] - mu * sc;
    }
    __syncthreads();
    const int tr = (tid >> 4) << 3, tc = (tid & 15) << 2;
    const int m = tid & 127, kk = (tid >> 7) << 3;
    const int bk = tid >> 4, bn = (tid & 15) << 2;
    const float* aSrc = Gb + (size_t)(row0 + m) * DD + kk;
    const float* bSrc = Wb + (size_t)bk * DD + col0 + bn;

    float acc[8][4] = {};
    float4 pa0 = *(const float4*)(aSrc);
    float4 pa1 = *(const float4*)(aSrc + 4);
    float4 pb  = *(const float4*)(bSrc);
    for (int t = 0; t < DD / 16; ++t) {
        const int cur = t & 1;
        {
            const int kg = t * 16 + kk;
            float vv[8] = {pa0.x, pa0.y, pa0.z, pa0.w, pa1.x, pa1.y, pa1.z, pa1.w};
            #pragma unroll
            for (int i = 0; i < 8; ++i) {
                float v = fmaf(vv[i], scs[kg + i], shs[kg + i]);
                Asm[cur][kk + i][m] = v > 0.f ? v : 0.f;
            }
            *(float4*)&Bsm[cur][bk][bn] = pb;
        }
        __syncthreads();
        if (t < DD / 16 - 1) {
            const int k0 = (t + 1) * 16;
            pa0 = *(const float4*)(aSrc + k0);
            pa1 = *(const float4*)(aSrc + k0 + 4);
            pb  = *(const float4*)(bSrc + (size_t)k0 * DD);
        }
        #pragma unroll
        for (int k = 0; k < 16; ++k) {
            float a[8], bv[4];
            *(float4*)&a[0] = *(const float4*)&Asm[cur][k][tr];
            *(float4*)&a[4] = *(const float4*)&Asm[cur][k][tr + 4];
            *(float4*)&bv[0] = *(const float4*)&Bsm[cur][k][tc];
            #pragma unroll
            for (int i = 0; i < 8; ++i)
                #pragma unroll
                for (int j = 0; j < 4; ++j)
                    acc[i][j] = fmaf(a[i], bv[j], acc[i][j]);
        }
    }
    float bias4[4];
    *(float4*)bias4 = *(const float4*)(bb + col0 + tc);
    #pragma unroll
    for (int i = 0; i < 8; ++i) {
        size_t idx = (size_t)(row0 + tr + i) * DD + col0 + tc;
        float4 o;
        o.x = acc[i][0] + bias4[0]; o.y = acc[i][1] + bias4[1];
        o.z = acc[i][2] + bias4[2]; o.w = acc[i][3] + bias4[3];
        *(float4*)(O + idx) = o;
        if (first) {
            *(float4*)(Ab + idx) = o;
        } else {
            float4 p = *(const float4*)(Ab + idx);
            p.x += o.x; p.y += o.y; p.z += o.z; p.w += o.w;
            *(float4*)(Ab + idx) = p;
        }
    }
}

__global__ __launch_bounds__(256)
void mse_partial(const float* __restrict__ accb, double* __restrict__ msep)
{
    const int pair = blockIdx.x;
    const float* A_ = accb + (size_t)pair * NN * DD;
    const float* B_ = accb + (size_t)3 * NN * DD;
    const size_t total = (size_t)NN * DD;
    double s = 0.0;
    for (size_t i = (size_t)blockIdx.y * blockDim.x + threadIdx.x; i < total;
         i += (size_t)gridDim.y * blockDim.x) {
        float d = A_[i] - B_[i];
        s += (double)d * (double)d;
    }
    __shared__ double red[256];
    red[threadIdx.x] = s;
    __syncthreads();
    for (int st = 128; st > 0; st >>= 1) {
        if (threadIdx.x < st) red[threadIdx.x] += red[threadIdx.x + st];
        __syncthreads();
    }
    if (threadIdx.x == 0) atomicAdd(&msep[pair], red[0]);
}

__global__ void mse_final(const double* __restrict__ msep, float* __restrict__ out)
{
    int i = threadIdx.x;
    if (i < 3) out[i] = (float)(msep[i] / ((double)NN * DD) / 9.0);
}

static inline Ptrs4 mk4(const float* a, const float* b, const float* c, const float* d) {
    Ptrs4 p; p.p0 = a; p.p1 = b; p.p2 = c; p.p3 = d; return p;
}

extern "C" void kernel_launch(void* const* d_in, const int* in_sizes, int n_in,
                              void* d_out, int out_size, void* d_ws, size_t ws_size,
                              hipStream_t stream)
{
    (void)in_sizes; (void)n_in; (void)out_size;
    const float* adjW[3]  = {(const float*)d_in[4],  (const float*)d_in[9],  (const float*)d_in[14]};
    const float* adjb[3]  = {(const float*)d_in[5],  (const float*)d_in[10], (const float*)d_in[15]};
    const float* mlpW[3]  = {(const float*)d_in[6],  (const float*)d_in[11], (const float*)d_in[16]};
    const float* mlpb[3]  = {(const float*)d_in[7],  (const float*)d_in[12], (const float*)d_in[17]};
    const float* mlpbn[3] = {(const float*)d_in[8],  (const float*)d_in[13], (const float*)d_in[18]};

    char* ws = (char*)d_ws;
    double* msep  = (double*)ws;                 // [3]
    float* colsum = (float*)(ws + 64);           // [3][4][256]
    float* bnsum  = colsum + 3 * 4 * DD;
    float* bnsq   = bnsum  + 3 * 4 * DD;
    float* tvals  = bnsq   + 3 * 4 * DD;         // [4]
    const size_t tensN = (size_t)4 * NN * DD;             // elements per fp32 tensor set
    const size_t HS_BYTES = (size_t)4 * 3 * DD * NN * 2;  // 25.17 MB split region
    const size_t MASK_BYTES = (size_t)4 * NN * (NN / 8);  // 8.39 MB

    float* Xbuf = (float*)(ws + 65536);
    float* Abuf = Xbuf + tensN;

    const size_t need_fast = 65536 + 2 * tensN * 4 + HS_BYTES + tensN * 4 + MASK_BYTES;
    const bool fast = ws_size >= need_fast;

    float* Bbuf = nullptr; float* accb; uint8_t* mask;
    ushort_t *Sh, *Sm, *Sl, *HsG = nullptr;
    if (fast) {
        char* hr = (char*)(Abuf + tensN);
        HsG  = (ushort_t*)hr;
        Sl   = (ushort_t*)hr;
        accb = (float*)(hr + HS_BYTES);
        mask = (uint8_t*)(accb + tensN);
    } else {
        Bbuf = Abuf + tensN;
        accb = Bbuf + tensN;
        mask = (uint8_t*)(accb + tensN);
        Sl   = (ushort_t*)Bbuf;
    }
    Sh = (ushort_t*)Abuf;
    Sm = Sh + tensN;

    hipMemsetAsync(ws, 0, 64 + 3 * 3 * 4 * DD * sizeof(float), stream);
    for (int b = 0; b < 4; ++b)
        hipMemcpyAsync(Xbuf + (size_t)b * NN * DD, d_in[b], (size_t)NN * DD * sizeof(float),
                       hipMemcpyDeviceToDevice, stream);

    dim3 gS(4, 32, 4);      // fp32 GEMMs / masked_mfma (64-col tiles)
    dim3 gA(528, 1, 4);     // adj tiles, compact upper-tri
    dim3 gT(64, 4, 4);      // tsplit_x
    dim3 blk(256);

    for (int l = 0; l < NL; ++l) {
        float* cs_l = colsum + l * 4 * DD;
        float* bs_l = bnsum + l * 4 * DD;
        float* bq_l = bnsq  + l * 4 * DD;
        #define MK(arr, off) mk4(arr[0] + (off), arr[1] + (off), arr[2] + (off), arr[1] + (off))
        // h1 = elu(X @ aW0 + ab0)  -> Abuf
        gemm_small<0><<<gS, blk, 0, stream>>>(Xbuf, MK(adjW, 0), MK(adjb, 0), Abuf,
                                              nullptr, nullptr, (ushort_t*)nullptr);
        if (fast) {
            // h2 = elu(h1 @ aW1 + ab1) -> bf16 3-split Hs + colsum (no fp32 h2)
            gemm_small<3><<<gS, blk, 0, stream>>>(Abuf, MK(adjW, (size_t)DD * DD), MK(adjb, DD),
                                                  nullptr, cs_l, nullptr, HsG);
            thresh_k<<<4, blk, 0, stream>>>(cs_l, tvals);
            adj_mfma_v2<<<gA, blk, 0, stream>>>(HsG, tvals, mask);
        } else {
            gemm_small<1><<<gS, blk, 0, stream>>>(Abuf, MK(adjW, (size_t)DD * DD), MK(adjb, DD),
                                                  Bbuf, cs_l, nullptr, (ushort_t*)nullptr);
            thresh_k<<<4, blk, 0, stream>>>(cs_l, tvals);
            adj_mfma_s<<<gA, blk, 0, stream>>>(Bbuf, tvals, mask);
        }
        // splits of X^T (h1 dead; Hs dead after adj) -> Sh,Sm (Abuf), Sl
        tsplit_x<<<gT, blk, 0, stream>>>(Xbuf, Sh, Sm, Sl);
        // X = X + M @ X   (in-place Xbuf)
        masked_mfma<<<gS, blk, 0, stream>>>(Xbuf, Sh, Sm, Sl, mask);
        const size_t w0 = (size_t)l * 2 * DD * DD, b0 = (size_t)l * 2 * DD;
        // g = X' @ mW0 + mb0 + BN stats  -> Abuf (splits dead)
        gemm_small<2><<<gS, blk, 0, stream>>>(Xbuf, MK(mlpW, w0), MK(mlpb, b0), Abuf,
                                              bs_l, bq_l, (ushort_t*)nullptr);
        // X = relu(bn(g)) @ mW1 + mb1;  acc (+)= X  -> Xbuf
        gemm_bnrelu<<<gS, blk, 0, stream>>>(Abuf, MK(mlpW, w0 + (size_t)DD * DD), MK(mlpb, b0 + DD),
                                            MK(mlpbn, b0), bs_l, bq_l, Xbuf, accb, (l == 0) ? 1 : 0);
        #undef MK
    }
    mse_partial<<<dim3(3, 64), blk, 0, stream>>>(accb, msep);
    mse_final<<<1, 64, 0, stream>>>(msep, (float*)d_out);
}

// Round 10
// 1163.982 us; speedup vs baseline: 1.0868x; 1.0868x over previous
//
#include <hip/hip_runtime.h>
#include <hip/hip_bf16.h>
#include <stdint.h>

#define NN 4096
#define DD 256
#define NL 3
typedef unsigned int uint;
typedef unsigned short ushort_t;

typedef float f32x4 __attribute__((ext_vector_type(4)));
typedef short bf16x8 __attribute__((ext_vector_type(8)));

struct Ptrs4 { const float* p0; const float* p1; const float* p2; const float* p3; };
__device__ __forceinline__ const float* sel(const Ptrs4& p, int b) {
    return b == 0 ? p.p0 : b == 1 ? p.p1 : b == 2 ? p.p2 : p.p3;
}

// packed bf16 pair (RNE), low half = a, high half = b
__device__ __forceinline__ uint pkbf2(float a, float b) {
    __hip_bfloat162 t = __float22bfloat162_rn(float2{a, b});
    union { __hip_bfloat162 h; uint u; } c; c.h = t; return c.u;
}
// exact 3-way split of a pair: x = h + m + l + r, |r| <= ~2^-27 |x|
__device__ __forceinline__ void split3_pk(float a, float b, uint& h, uint& m, uint& l) {
    h = pkbf2(a, b);
    float ha = __uint_as_float(h << 16), hb = __uint_as_float(h & 0xFFFF0000u);
    float ra = a - ha, rb = b - hb;
    m = pkbf2(ra, rb);
    float ma = __uint_as_float(m << 16), mb = __uint_as_float(m & 0xFFFF0000u);
    l = pkbf2(ra - ma, rb - mb);
}

// async global->LDS; LDS dest = wave-uniform base + lane*size; global src per-lane
typedef __attribute__((address_space(3))) uint lds_u32;
typedef __attribute__((address_space(1))) const uint glb_u32;
__device__ __forceinline__ void gload16(void* l, const void* g) {
    __builtin_amdgcn_global_load_lds((glb_u32*)g, (lds_u32*)l, 16, 0, 0);
}
__device__ __forceinline__ void gload4(void* l, const void* g) {
    __builtin_amdgcn_global_load_lds((glb_u32*)g, (lds_u32*)l, 4, 0, 0);
}

// ---------------------------------------------------------------------------
// fp32 GEMM (R6-proven: 64-col tiles + register prefetch, 2 barriers/tile —
// the second barrier pins ds_writes after compute so prefetch latency hides
// under the FMA block; R9 showed removing it regresses). Bit-exact chain.
// MODE 0: elu; MODE 1: elu + colsum (fallback); MODE 2: linear + BN stats;
// MODE 3: elu + colsum, bf16 3-split out in Hs[lvl][d/8][n][8] layout.
// ---------------------------------------------------------------------------
template<int MODE>
__global__ __launch_bounds__(256, 4)
void gemm_small(const float* __restrict__ Xin, Ptrs4 Wp, Ptrs4 bp,
                float* __restrict__ Out, float* __restrict__ cs, float* __restrict__ csq,
                ushort_t* __restrict__ Hso)
{
    const int b = blockIdx.z;
    const float* Wb = sel(Wp, b);
    const float* bb = sel(bp, b);
    const float* X = Xin + (size_t)b * NN * DD;
    float* O = Out + (size_t)b * NN * DD;
    ushort_t* HsO = Hso + (size_t)b * 3 * (size_t)DD * NN;
    const int row0 = blockIdx.y * 128, col0 = blockIdx.x * 64;
    const int tid = threadIdx.x;
    __shared__ float Asm[16][132];
    __shared__ float Bsm[16][68];
    const int tr = (tid >> 4) << 3, tc = (tid & 15) << 2;
    const int m = tid & 127, kk = (tid >> 7) << 3;
    const int bk = tid >> 4, bn = (tid & 15) << 2;
    const float* aSrc = X + (size_t)(row0 + m) * DD + kk;
    const float* bSrc = Wb + (size_t)bk * DD + col0 + bn;

    float acc[8][4] = {};
    float4 pa0 = *(const float4*)(aSrc);
    float4 pa1 = *(const float4*)(aSrc + 4);
    float4 pb  = *(const float4*)(bSrc);
    for (int t = 0; t < DD / 16; ++t) {
        Asm[kk+0][m]=pa0.x; Asm[kk+1][m]=pa0.y; Asm[kk+2][m]=pa0.z; Asm[kk+3][m]=pa0.w;
        Asm[kk+4][m]=pa1.x; Asm[kk+5][m]=pa1.y; Asm[kk+6][m]=pa1.z; Asm[kk+7][m]=pa1.w;
        *(float4*)&Bsm[bk][bn] = pb;
        __syncthreads();
        if (t < DD / 16 - 1) {
            const int k0 = (t + 1) * 16;
            pa0 = *(const float4*)(aSrc + k0);
            pa1 = *(const float4*)(aSrc + k0 + 4);
            pb  = *(const float4*)(bSrc + (size_t)k0 * DD);
        }
        #pragma unroll
        for (int k = 0; k < 16; ++k) {
            float a[8], bv[4];
            *(float4*)&a[0] = *(const float4*)&Asm[k][tr];
            *(float4*)&a[4] = *(const float4*)&Asm[k][tr + 4];
            *(float4*)&bv[0] = *(const float4*)&Bsm[k][tc];
            #pragma unroll
            for (int i = 0; i < 8; ++i)
                #pragma unroll
                for (int j = 0; j < 4; ++j)
                    acc[i][j] = fmaf(a[i], bv[j], acc[i][j]);
        }
        __syncthreads();
    }
    float bias4[4];
    *(float4*)bias4 = *(const float4*)(bb + col0 + tc);
    float s4[4] = {0.f,0.f,0.f,0.f}, q4[4] = {0.f,0.f,0.f,0.f};
    // MODE 3 split-store geometry: d = col0+tc (mult of 4), layout [lvl][d>>3][n][8]
    const int dph = col0 + tc;
    const size_t sb3 = (size_t)(dph >> 3) * (NN * 8) + (dph & 4);
    #pragma unroll
    for (int i = 0; i < 8; ++i) {
        float ov[4];
        #pragma unroll
        for (int j = 0; j < 4; ++j) {
            float v = acc[i][j] + bias4[j];
            if (MODE == 0 || MODE == 1 || MODE == 3) v = (v > 0.f) ? v : (expf(v) - 1.f);
            ov[j] = v;
            if (MODE == 1 || MODE == 3) s4[j] += v;
            if (MODE == 2) { s4[j] += v; q4[j] += v * v; }
        }
        if (MODE == 3) {
            uint2 vh, vm, vl;
            split3_pk(ov[0], ov[1], vh.x, vm.x, vl.x);
            split3_pk(ov[2], ov[3], vh.y, vm.y, vl.y);
            size_t off = sb3 + (size_t)(row0 + tr + i) * 8;
            *(uint2*)(HsO + off) = vh;
            *(uint2*)(HsO + (size_t)DD * NN + off) = vm;
            *(uint2*)(HsO + (size_t)2 * DD * NN + off) = vl;
        } else {
            float4 o; o.x = ov[0]; o.y = ov[1]; o.z = ov[2]; o.w = ov[3];
            *(float4*)(O + (size_t)(row0 + tr + i) * DD + col0 + tc) = o;
        }
    }
    if (MODE == 1 || MODE == 2 || MODE == 3) {
        __syncthreads();
        const int rg = tid >> 4;
        #pragma unroll
        for (int j = 0; j < 4; ++j) {
            Asm[rg][tc + j] = s4[j];
            if (MODE == 2) Bsm[rg][tc + j] = q4[j];
        }
        __syncthreads();
        if (tid < 64) {
            float s = 0.f, q = 0.f;
            #pragma unroll
            for (int r = 0; r < 16; ++r) { s += Asm[r][tid]; if (MODE == 2) q += Bsm[r][tid]; }
            atomicAdd(&cs[b * DD + col0 + tid], s);
            if (MODE == 2) atomicAdd(&csq[b * DD + col0 + tid], q);
        }
    }
}

// threshold per branch: t = ||colsum||^2 / N^2
__global__ void thresh_k(const float* __restrict__ cs, float* __restrict__ tvals)
{
    const int b = blockIdx.x, t = threadIdx.x;
    __shared__ float red[256];
    float v = cs[b * DD + t];
    red[t] = v * v;
    __syncthreads();
    for (int s = 128; s > 0; s >>= 1) { if (t < s) red[t] += red[t + s]; __syncthreads(); }
    if (t == 0) tvals[b] = red[0] * (1.0f / 16777216.0f);
}

// ---------------------------------------------------------------------------
// transpose + exact 3-split: X[b][n][d] fp32 -> S{h,m,l}[b][d][j=n] bf16.
// ---------------------------------------------------------------------------
__global__ __launch_bounds__(256)
void tsplit_x(const float* __restrict__ Xin, ushort_t* __restrict__ Sh,
              ushort_t* __restrict__ Sm, ushort_t* __restrict__ Sl)
{
    const int b = blockIdx.z;
    const int n0 = blockIdx.x * 64, d0 = blockIdx.y * 64;
    const float* X = Xin + (size_t)b * NN * DD;
    __shared__ float ls[64][65];
    const int tid = threadIdx.x;
    #pragma unroll
    for (int i = 0; i < 4; ++i) {
        int u = (i << 8) + tid;
        int r = u >> 4, c4 = (u & 15) << 2;   // r = n-row, c4 = d offset
        float4 v = *(const float4*)(X + (size_t)(n0 + r) * DD + d0 + c4);
        ls[r][c4] = v.x; ls[r][c4+1] = v.y; ls[r][c4+2] = v.z; ls[r][c4+3] = v.w;
    }
    __syncthreads();
    const int d = tid >> 2, seg = (tid & 3) << 4;   // 16 n-values per thread
    uint ph[8], pm[8], pl[8];
    #pragma unroll
    for (int jj = 0; jj < 8; ++jj) {
        float a = ls[seg + 2 * jj][d];
        float c = ls[seg + 2 * jj + 1][d];
        split3_pk(a, c, ph[jj], pm[jj], pl[jj]);
    }
    size_t idx = ((size_t)(b * DD + d0 + d)) * NN + n0 + seg;   // ushort units
    *(uint4*)(Sh + idx)     = *(uint4*)&ph[0];
    *(uint4*)(Sh + idx + 8) = *(uint4*)&ph[4];
    *(uint4*)(Sm + idx)     = *(uint4*)&pm[0];
    *(uint4*)(Sm + idx + 8) = *(uint4*)&pm[4];
    *(uint4*)(Sl + idx)     = *(uint4*)&pl[0];
    *(uint4*)(Sl + idx + 8) = *(uint4*)&pl[4];
}

// ---------------------------------------------------------------------------
// adj v1 (fallback, proven): fp32 staging + in-tile split.
// ---------------------------------------------------------------------------
__global__ __launch_bounds__(256, 3)
void adj_mfma_s(const float* __restrict__ H, const float* __restrict__ tvals,
                uint8_t* __restrict__ mask)
{
    int t = blockIdx.x;
    int by = 0, rem = 32;
    while (t >= rem) { t -= rem; rem--; by++; }
    const int bx = by + t;
    const int b = blockIdx.z;
    const int row0 = by * 128, col0 = bx * 128;
    const int tid = threadIdx.x;
    const int wave = tid >> 6, ln = tid & 15, quad = (tid >> 4) & 3;
    const int wrow = wave >> 1, wcol = wave & 1;
    const float* Hb = H + (size_t)b * NN * DD;
    uint8_t* Mb = mask + (size_t)b * NN * (NN / 8);
    __shared__ ushort_t hs[2][3][128][34];

    f32x4 acc[4][4] = {};
    for (int k0 = 0; k0 < DD; k0 += 32) {
        #pragma unroll
        for (int i = 0; i < 8; ++i) {
            int f = (i << 8) + tid;
            int sr = f >> 3;
            int side = sr >> 7, r = sr & 127, part = f & 7;
            int grow = (side ? col0 : row0) + r;
            float4 v = *(const float4*)(Hb + (size_t)grow * DD + k0 + part * 4);
            uint h0, m0, l0, h1, m1, l1;
            split3_pk(v.x, v.y, h0, m0, l0);
            split3_pk(v.z, v.w, h1, m1, l1);
            uint2 ph; ph.x = h0; ph.y = h1;
            uint2 pm; pm.x = m0; pm.y = m1;
            uint2 pl; pl.x = l0; pl.y = l1;
            *(uint2*)&hs[side][0][r][part * 4] = ph;
            *(uint2*)&hs[side][1][r][part * 4] = pm;
            *(uint2*)&hs[side][2][r][part * 4] = pl;
        }
        __syncthreads();
        bf16x8 af[4][3];
        #pragma unroll
        for (int mt = 0; mt < 4; ++mt)
            #pragma unroll
            for (int lvl = 0; lvl < 3; ++lvl)
                af[mt][lvl] = *(const bf16x8*)&hs[0][lvl][wrow * 64 + mt * 16 + ln][quad * 8];
        #pragma unroll
        for (int nt = 0; nt < 4; ++nt) {
            int n = wcol * 64 + nt * 16 + ln;
            bf16x8 bh = *(const bf16x8*)&hs[1][0][n][quad * 8];
            bf16x8 bm = *(const bf16x8*)&hs[1][1][n][quad * 8];
            bf16x8 bl = *(const bf16x8*)&hs[1][2][n][quad * 8];
            #pragma unroll
            for (int mt = 0; mt < 4; ++mt) {
                f32x4 a = acc[mt][nt];
                a = __builtin_amdgcn_mfma_f32_16x16x32_bf16(af[mt][0], bh, a, 0, 0, 0);
                a = __builtin_amdgcn_mfma_f32_16x16x32_bf16(af[mt][0], bm, a, 0, 0, 0);
                a = __builtin_amdgcn_mfma_f32_16x16x32_bf16(af[mt][1], bh, a, 0, 0, 0);
                a = __builtin_amdgcn_mfma_f32_16x16x32_bf16(af[mt][0], bl, a, 0, 0, 0);
                a = __builtin_amdgcn_mfma_f32_16x16x32_bf16(af[mt][2], bh, a, 0, 0, 0);
                a = __builtin_amdgcn_mfma_f32_16x16x32_bf16(af[mt][1], bm, a, 0, 0, 0);
                acc[mt][nt] = a;
            }
        }
        __syncthreads();
    }
    const float t2 = tvals[b];
    #pragma unroll
    for (int mt = 0; mt < 4; ++mt)
        #pragma unroll
        for (int nt = 0; nt < 4; ++nt) {
            bool p0 = acc[mt][nt][0] > t2, p1 = acc[mt][nt][1] > t2;
            bool p2 = acc[mt][nt][2] > t2, p3 = acc[mt][nt][3] > t2;
            unsigned long long bal[4];
            bal[0] = __ballot(p0); bal[1] = __ballot(p1);
            bal[2] = __ballot(p2); bal[3] = __ballot(p3);
            if ((tid & 63) < 16) {
                int q = ln >> 2, rsel = ln & 3;
                unsigned long long bv = rsel == 0 ? bal[0] : rsel == 1 ? bal[1]
                                       : rsel == 2 ? bal[2] : bal[3];
                ushort_t u16 = (ushort_t)((bv >> (q * 16)) & 0xFFFFull);
                int row = row0 + wrow * 64 + mt * 16 + ln;
                int colb = (col0 + wcol * 64 + nt * 16) >> 3;
                *(ushort_t*)(Mb + (size_t)row * (NN / 8) + colb) = u16;
            }
            uint nib = (p0 ? 1u : 0u) | (p1 ? 2u : 0u) | (p2 ? 4u : 0u) | (p3 ? 8u : 0u);
            uint other = (uint)__shfl_xor((int)nib, 16);
            if ((quad & 1) == 0) {
                uint byt = nib | (other << 4);
                int rowm = col0 + wcol * 64 + nt * 16 + ln;
                int colbm = ((row0 + wrow * 64 + mt * 16) >> 3) + (quad >> 1);
                Mb[(size_t)rowm * (NN / 8) + colbm] = (uint8_t)byt;
            }
        }
}

// ---------------------------------------------------------------------------
// adj v2 (fast path): pure bf16 MFMA from precomputed splits. (R0-proven DMA)
// ---------------------------------------------------------------------------
__global__ __launch_bounds__(256, 3)
void adj_mfma_v2(const ushort_t* __restrict__ Hs, const float* __restrict__ tvals,
                 uint8_t* __restrict__ mask)
{
    int t = blockIdx.x;
    int by = 0, rem = 32;
    while (t >= rem) { t -= rem; rem--; by++; }
    const int bx = by + t;
    const int b = blockIdx.z;
    const int row0 = by * 128, col0 = bx * 128;
    const int tid = threadIdx.x;
    const int wave = tid >> 6, ln = tid & 15, quad = (tid >> 4) & 3;
    const int wrow = wave >> 1, wcol = wave & 1;
    const ushort_t* Hb = Hs + (size_t)b * 3 * (size_t)DD * NN;
    uint8_t* Mb = mask + (size_t)b * NN * (NN / 8);
    __shared__ ushort_t hs2[6][4][128][8];   // 48 KB, linear (DMA-friendly)

    const int grow = tid & 127;
    const int qb = tid >> 7;                  // 0/1
    const size_t var0 = (size_t)qb * (NN * 8) + (size_t)(row0 + grow) * 8;
    const size_t var1 = (size_t)qb * (NN * 8) + (size_t)(col0 + grow) * 8;

    f32x4 acc[4][4] = {};
    for (int kb0 = 0; kb0 < DD / 8; kb0 += 4) {     // 32 k per iter
        #pragma unroll
        for (int c = 0; c < 12; ++c) {
            const int sl = c >> 1, part = c & 1;    // sl = side*3+lvl
            const int side = sl / 3, lvl = sl % 3;
            const ushort_t* g = Hb + (size_t)lvl * DD * NN
                                   + (size_t)(kb0 + part * 2) * (NN * 8)
                                   + (side ? var1 : var0);
            char* l = (char*)&hs2[0][0][0][0] + (((sl * 8 + part * 4 + wave)) << 10);
            gload16(l, g);
        }
        __syncthreads();
        bf16x8 af[4][3];
        #pragma unroll
        for (int mt = 0; mt < 4; ++mt)
            #pragma unroll
            for (int lvl = 0; lvl < 3; ++lvl)
                af[mt][lvl] = *(const bf16x8*)&hs2[lvl][quad][wrow * 64 + mt * 16 + ln][0];
        #pragma unroll
        for (int nt = 0; nt < 4; ++nt) {
            const int n = wcol * 64 + nt * 16 + ln;
            bf16x8 bh = *(const bf16x8*)&hs2[3][quad][n][0];
            bf16x8 bm = *(const bf16x8*)&hs2[4][quad][n][0];
            bf16x8 bl = *(const bf16x8*)&hs2[5][quad][n][0];
            #pragma unroll
            for (int mt = 0; mt < 4; ++mt) {
                f32x4 a = acc[mt][nt];
                a = __builtin_amdgcn_mfma_f32_16x16x32_bf16(af[mt][0], bh, a, 0, 0, 0);
                a = __builtin_amdgcn_mfma_f32_16x16x32_bf16(af[mt][0], bm, a, 0, 0, 0);
                a = __builtin_amdgcn_mfma_f32_16x16x32_bf16(af[mt][1], bh, a, 0, 0, 0);
                a = __builtin_amdgcn_mfma_f32_16x16x32_bf16(af[mt][0], bl, a, 0, 0, 0);
                a = __builtin_amdgcn_mfma_f32_16x16x32_bf16(af[mt][2], bh, a, 0, 0, 0);
                a = __builtin_amdgcn_mfma_f32_16x16x32_bf16(af[mt][1], bm, a, 0, 0, 0);
                acc[mt][nt] = a;
            }
        }
        __syncthreads();
    }
    const float t2 = tvals[b];
    #pragma unroll
    for (int mt = 0; mt < 4; ++mt)
        #pragma unroll
        for (int nt = 0; nt < 4; ++nt) {
            bool p0 = acc[mt][nt][0] > t2, p1 = acc[mt][nt][1] > t2;
            bool p2 = acc[mt][nt][2] > t2, p3 = acc[mt][nt][3] > t2;
            unsigned long long bal[4];
            bal[0] = __ballot(p0); bal[1] = __ballot(p1);
            bal[2] = __ballot(p2); bal[3] = __ballot(p3);
            if ((tid & 63) < 16) {
                int q = ln >> 2, rsel = ln & 3;
                unsigned long long bv = rsel == 0 ? bal[0] : rsel == 1 ? bal[1]
                                       : rsel == 2 ? bal[2] : bal[3];
                ushort_t u16 = (ushort_t)((bv >> (q * 16)) & 0xFFFFull);
                int row = row0 + wrow * 64 + mt * 16 + ln;
                int colb = (col0 + wcol * 64 + nt * 16) >> 3;
                *(ushort_t*)(Mb + (size_t)row * (NN / 8) + colb) = u16;
            }
            uint nib = (p0 ? 1u : 0u) | (p1 ? 2u : 0u) | (p2 ? 4u : 0u) | (p3 ? 8u : 0u);
            uint other = (uint)__shfl_xor((int)nib, 16);
            if ((quad & 1) == 0) {
                uint byt = nib | (other << 4);
                int rowm = col0 + wcol * 64 + nt * 16 + ln;
                int colbm = ((row0 + wrow * 64 + mt * 16) >> 3) + (quad >> 1);
                Mb[(size_t)rowm * (NN / 8) + colbm] = (uint8_t)byt;
            }
        }
}

// ---------------------------------------------------------------------------
// X' = X + M @ X via MFMA, IN-PLACE into X.  (R3 DMA dbuf + XOR swz +
// R7-proven 256x16B LDS decode LUT.)
// ---------------------------------------------------------------------------
__global__ __launch_bounds__(256)
void masked_mfma(float* __restrict__ Xio, const ushort_t* __restrict__ Sh,
                 const ushort_t* __restrict__ Sm, const ushort_t* __restrict__ Sl,
                 const uint8_t* __restrict__ mask)
{
    const int b = blockIdx.z;
    const int row0 = blockIdx.y * 128, col0 = blockIdx.x * 64;
    const int tid = threadIdx.x;
    const int wave = tid >> 6, ln = tid & 15, quad = (tid >> 4) & 3;
    const int wrow = wave >> 1, wcol = wave & 1;
    float* X = Xio + (size_t)b * NN * DD;
    const size_t sb = (size_t)b * DD * NN;
    const ushort_t* Ss[3] = { Sh + sb, Sm + sb, Sl + sb };
    const uint* Mw = (const uint*)(mask + (size_t)b * NN * (NN / 8));
    __shared__ ushort_t bt2[2][3][2][64][32];   // [buf][lvl][khalf][col][32j], 48 KB
    __shared__ uint msk2[2][2][128];            // [buf][khalf][row], 2 KB
    __shared__ uint lut[256][4];                // byte -> bf16x8 mask row, 4 KB

    // build decode LUT (bit-identical to the arithmetic decode)
    #pragma unroll
    for (int p = 0; p < 4; ++p)
        lut[tid][p] = (((tid >> (2 * p)) & 1u) ? 0x3F80u : 0u) |
                      (((tid >> (2 * p + 1)) & 1u) ? 0x3F800000u : 0u);

    const int c = tid >> 2;
    const int qp = (tid & 3) ^ ((tid >> 3) & 3);
    const size_t goff = (size_t)(col0 + c) * NN + (size_t)qp * 8;  // + j
    const size_t mrow = (size_t)(row0 + (tid & 127)) * 128;        // uint units

    f32x4 acc[4][2] = {};

    #define STAGE(buf, t)                                                         \
        {                                                                         \
            const size_t j_ = (size_t)(t) * 64;                                   \
            _Pragma("unroll")                                                     \
            for (int lvl = 0; lvl < 3; ++lvl) {                                   \
                gload16((char*)&bt2[buf][lvl][0][0][0] + (wave << 10),            \
                        Ss[lvl] + goff + j_);                                     \
                gload16((char*)&bt2[buf][lvl][1][0][0] + (wave << 10),            \
                        Ss[lvl] + goff + j_ + 32);                                \
            }                                                                     \
            if (tid < 128) {                                                      \
                gload4((char*)&msk2[buf][0][0] + (wave << 8), Mw + mrow + 2*(t)); \
                gload4((char*)&msk2[buf][1][0] + (wave << 8), Mw + mrow + 2*(t)+1);\
            }                                                                     \
        }

    STAGE(0, 0);
    __syncthreads();   // also publishes the LUT

    for (int t = 0; t < NN / 64; ++t) {
        const int cur = t & 1;
        if (t < NN / 64 - 1) STAGE(cur ^ 1, t + 1);
        #pragma unroll
        for (int kk = 0; kk < 2; ++kk) {
            bf16x8 afr[4];
            #pragma unroll
            for (int mt = 0; mt < 4; ++mt) {
                uint w = msk2[cur][kk][wrow * 64 + mt * 16 + ln];
                uint byte = (w >> (quad * 8)) & 0xFFu;
                afr[mt] = *(const bf16x8*)&lut[byte][0];
            }
            #pragma unroll
            for (int nt = 0; nt < 2; ++nt) {
                const int n = wcol * 32 + nt * 16 + ln;
                const int slot = (quad ^ ((n >> 1) & 3)) * 8;
                bf16x8 bh = *(const bf16x8*)&bt2[cur][0][kk][n][slot];
                bf16x8 bm = *(const bf16x8*)&bt2[cur][1][kk][n][slot];
                bf16x8 bl = *(const bf16x8*)&bt2[cur][2][kk][n][slot];
                #pragma unroll
                for (int mt = 0; mt < 4; ++mt) {
                    f32x4 a = acc[mt][nt];
                    a = __builtin_amdgcn_mfma_f32_16x16x32_bf16(afr[mt], bh, a, 0, 0, 0);
                    a = __builtin_amdgcn_mfma_f32_16x16x32_bf16(afr[mt], bm, a, 0, 0, 0);
                    a = __builtin_amdgcn_mfma_f32_16x16x32_bf16(afr[mt], bl, a, 0, 0, 0);
                    acc[mt][nt] = a;
                }
            }
        }
        __syncthreads();
    }
    #undef STAGE
    #pragma unroll
    for (int mt = 0; mt < 4; ++mt)
        #pragma unroll
        for (int nt = 0; nt < 2; ++nt)
            #pragma unroll
            for (int r = 0; r < 4; ++r) {
                int row = row0 + wrow * 64 + mt * 16 + quad * 4 + r;
                int col = col0 + wcol * 32 + nt * 16 + ln;
                size_t idx = (size_t)row * DD + col;
                X[idx] = X[idx] + acc[mt][nt][r];
            }
}

// ---------------------------------------------------------------------------
// X = relu(bn(G)) @ W + bias;  acc (+)= X.  (R6-proven: reg prefetch, 2
// barriers/tile; BN at ds_write with identical op sequence => bit-exact.)
// ---------------------------------------------------------------------------
__global__ __launch_bounds__(256, 4)
void gemm_bnrelu(const float* __restrict__ G, Ptrs4 Wp, Ptrs4 bp, Ptrs4 gbp,
                 const float* __restrict__ bns, const float* __restrict__ bnq,
                 float* __restrict__ Xout, float* __restrict__ accb, int first)
{
    const int b = blockIdx.z;
    const float* Wb = sel(Wp, b);
    const float* bb = sel(bp, b);
    const float* gb = sel(gbp, b);
    const float* Gb = G + (size_t)b * NN * DD;
    float* O = Xout + (size_t)b * NN * DD;
    float* Ab = accb + (size_t)b * NN * DD;
    const int row0 = blockIdx.y * 128, col0 = blockIdx.x * 64;
    const int tid = threadIdx.x;
    __shared__ float Asm[16][132];
    __shared__ float Bsm[16][68];
    __shared__ float scs[DD], shs[DD];
    {
        float mu = bns[b * DD + tid] * (1.0f / NN);
        float ms = bnq[b * DD + tid] * (1.0f / NN);
        float var = ms - mu * mu;
        float sc = gb[tid] / sqrtf(var + 1e-5f);
        scs[tid] = sc;
        shs[tid] = gb[DD + tid] - mu * sc;
    }
    __syncthreads();
    const int tr = (tid >> 4) << 3, tc = (tid & 15) << 2;
    const int m = tid & 127, kk = (tid >> 7) << 3;
    const int bk = tid >> 4, bn = (tid & 15) << 2;
    const float* aSrc = Gb + (size_t)(row0 + m) * DD + kk;
    const float* bSrc = Wb + (size_t)bk * DD + col0 + bn;

    float acc[8][4] = {};
    float4 pa0 = *(const float4*)(aSrc);
    float4 pa1 = *(const float4*)(aSrc + 4);
    float4 pb  = *(const float4*)(bSrc);
    for (int t = 0; t < DD / 16; ++t) {
        {
            const int kg = t * 16 + kk;
            float vv[8] = {pa0.x, pa0.y, pa0.z, pa0.w, pa1.x, pa1.y, pa1.z, pa1.w};
            #pragma unroll
            for (int i = 0; i < 8; ++i) {
                float v = fmaf(vv[i], scs[kg + i], shs[kg + i]);
                Asm[kk + i][m] = v > 0.f ? v : 0.f;
            }
            *(float4*)&Bsm[bk][bn] = pb;
        }
        __syncthreads();
        if (t < DD / 16 - 1) {
            const int k0 = (t + 1) * 16;
            pa0 = *(const float4*)(aSrc + k0);
            pa1 = *(const float4*)(aSrc + k0 + 4);
            pb  = *(const float4*)(bSrc + (size_t)k0 * DD);
        }
        #pragma unroll
        for (int k = 0; k < 16; ++k) {
            float a[8], bv[4];
            *(float4*)&a[0] = *(const float4*)&Asm[k][tr];
            *(float4*)&a[4] = *(const float4*)&Asm[k][tr + 4];
            *(float4*)&bv[0] = *(const float4*)&Bsm[k][tc];
            #pragma unroll
            for (int i = 0; i < 8; ++i)
                #pragma unroll
                for (int j = 0; j < 4; ++j)
                    acc[i][j] = fmaf(a[i], bv[j], acc[i][j]);
        }
        __syncthreads();
    }
    float bias4[4];
    *(float4*)bias4 = *(const float4*)(bb + col0 + tc);
    #pragma unroll
    for (int i = 0; i < 8; ++i) {
        size_t idx = (size_t)(row0 + tr + i) * DD + col0 + tc;
        float4 o;
        o.x = acc[i][0] + bias4[0]; o.y = acc[i][1] + bias4[1];
        o.z = acc[i][2] + bias4[2]; o.w = acc[i][3] + bias4[3];
        *(float4*)(O + idx) = o;
        if (first) {
            *(float4*)(Ab + idx) = o;
        } else {
            float4 p = *(const float4*)(Ab + idx);
            p.x += o.x; p.y += o.y; p.z += o.z; p.w += o.w;
            *(float4*)(Ab + idx) = p;
        }
    }
}

__global__ __launch_bounds__(256)
void mse_partial(const float* __restrict__ accb, double* __restrict__ msep)
{
    const int pair = blockIdx.x;
    const float* A_ = accb + (size_t)pair * NN * DD;
    const float* B_ = accb + (size_t)3 * NN * DD;
    const size_t total = (size_t)NN * DD;
    double s = 0.0;
    for (size_t i = (size_t)blockIdx.y * blockDim.x + threadIdx.x; i < total;
         i += (size_t)gridDim.y * blockDim.x) {
        float d = A_[i] - B_[i];
        s += (double)d * (double)d;
    }
    __shared__ double red[256];
    red[threadIdx.x] = s;
    __syncthreads();
    for (int st = 128; st > 0; st >>= 1) {
        if (threadIdx.x < st) red[threadIdx.x] += red[threadIdx.x + st];
        __syncthreads();
    }
    if (threadIdx.x == 0) atomicAdd(&msep[pair], red[0]);
}

__global__ void mse_final(const double* __restrict__ msep, float* __restrict__ out)
{
    int i = threadIdx.x;
    if (i < 3) out[i] = (float)(msep[i] / ((double)NN * DD) / 9.0);
}

static inline Ptrs4 mk4(const float* a, const float* b, const float* c, const float* d) {
    Ptrs4 p; p.p0 = a; p.p1 = b; p.p2 = c; p.p3 = d; return p;
}

extern "C" void kernel_launch(void* const* d_in, const int* in_sizes, int n_in,
                              void* d_out, int out_size, void* d_ws, size_t ws_size,
                              hipStream_t stream)
{
    (void)in_sizes; (void)n_in; (void)out_size;
    const float* adjW[3]  = {(const float*)d_in[4],  (const float*)d_in[9],  (const float*)d_in[14]};
    const float* adjb[3]  = {(const float*)d_in[5],  (const float*)d_in[10], (const float*)d_in[15]};
    const float* mlpW[3]  = {(const float*)d_in[6],  (const float*)d_in[11], (const float*)d_in[16]};
    const float* mlpb[3]  = {(const float*)d_in[7],  (const float*)d_in[12], (const float*)d_in[17]};
    const float* mlpbn[3] = {(const float*)d_in[8],  (const float*)d_in[13], (const float*)d_in[18]};

    char* ws = (char*)d_ws;
    double* msep  = (double*)ws;                 // [3]
    float* colsum = (float*)(ws + 64);           // [3][4][256]
    float* bnsum  = colsum + 3 * 4 * DD;
    float* bnsq   = bnsum  + 3 * 4 * DD;
    float* tvals  = bnsq   + 3 * 4 * DD;         // [4]
    const size_t tensN = (size_t)4 * NN * DD;             // elements per fp32 tensor set
    const size_t HS_BYTES = (size_t)4 * 3 * DD * NN * 2;  // 25.17 MB split region
    const size_t MASK_BYTES = (size_t)4 * NN * (NN / 8);  // 8.39 MB

    float* Xbuf = (float*)(ws + 65536);
    float* Abuf = Xbuf + tensN;

    const size_t need_fast = 65536 + 2 * tensN * 4 + HS_BYTES + tensN * 4 + MASK_BYTES;
    const bool fast = ws_size >= need_fast;

    float* Bbuf = nullptr; float* accb; uint8_t* mask;
    ushort_t *Sh, *Sm, *Sl, *HsG = nullptr;
    if (fast) {
        char* hr = (char*)(Abuf + tensN);
        HsG  = (ushort_t*)hr;
        Sl   = (ushort_t*)hr;
        accb = (float*)(hr + HS_BYTES);
        mask = (uint8_t*)(accb + tensN);
    } else {
        Bbuf = Abuf + tensN;
        accb = Bbuf + tensN;
        mask = (uint8_t*)(accb + tensN);
        Sl   = (ushort_t*)Bbuf;
    }
    Sh = (ushort_t*)Abuf;
    Sm = Sh + tensN;

    hipMemsetAsync(ws, 0, 64 + 3 * 3 * 4 * DD * sizeof(float), stream);
    for (int b = 0; b < 4; ++b)
        hipMemcpyAsync(Xbuf + (size_t)b * NN * DD, d_in[b], (size_t)NN * DD * sizeof(float),
                       hipMemcpyDeviceToDevice, stream);

    dim3 gS(4, 32, 4);      // fp32 GEMMs / masked_mfma (64-col tiles)
    dim3 gA(528, 1, 4);     // adj tiles, compact upper-tri
    dim3 gT(64, 4, 4);      // tsplit_x
    dim3 blk(256);

    for (int l = 0; l < NL; ++l) {
        float* cs_l = colsum + l * 4 * DD;
        float* bs_l = bnsum + l * 4 * DD;
        float* bq_l = bnsq  + l * 4 * DD;
        #define MK(arr, off) mk4(arr[0] + (off), arr[1] + (off), arr[2] + (off), arr[1] + (off))
        // h1 = elu(X @ aW0 + ab0)  -> Abuf
        gemm_small<0><<<gS, blk, 0, stream>>>(Xbuf, MK(adjW, 0), MK(adjb, 0), Abuf,
                                              nullptr, nullptr, (ushort_t*)nullptr);
        if (fast) {
            // h2 = elu(h1 @ aW1 + ab1) -> bf16 3-split Hs + colsum (no fp32 h2)
            gemm_small<3><<<gS, blk, 0, stream>>>(Abuf, MK(adjW, (size_t)DD * DD), MK(adjb, DD),
                                                  nullptr, cs_l, nullptr, HsG);
            thresh_k<<<4, blk, 0, stream>>>(cs_l, tvals);
            adj_mfma_v2<<<gA, blk, 0, stream>>>(HsG, tvals, mask);
        } else {
            gemm_small<1><<<gS, blk, 0, stream>>>(Abuf, MK(adjW, (size_t)DD * DD), MK(adjb, DD),
                                                  Bbuf, cs_l, nullptr, (ushort_t*)nullptr);
            thresh_k<<<4, blk, 0, stream>>>(cs_l, tvals);
            adj_mfma_s<<<gA, blk, 0, stream>>>(Bbuf, tvals, mask);
        }
        // splits of X^T (h1 dead; Hs dead after adj) -> Sh,Sm (Abuf), Sl
        tsplit_x<<<gT, blk, 0, stream>>>(Xbuf, Sh, Sm, Sl);
        // X = X + M @ X   (in-place Xbuf)
        masked_mfma<<<gS, blk, 0, stream>>>(Xbuf, Sh, Sm, Sl, mask);
        const size_t w0 = (size_t)l * 2 * DD * DD, b0 = (size_t)l * 2 * DD;
        // g = X' @ mW0 + mb0 + BN stats  -> Abuf (splits dead)
        gemm_small<2><<<gS, blk, 0, stream>>>(Xbuf, MK(mlpW, w0), MK(mlpb, b0), Abuf,
                                              bs_l, bq_l, (ushort_t*)nullptr);
        // X = relu(bn(g)) @ mW1 + mb1;  acc (+)= X  -> Xbuf
        gemm_bnrelu<<<gS, blk, 0, stream>>>(Abuf, MK(mlpW, w0 + (size_t)DD * DD), MK(mlpb, b0 + DD),
                                            MK(mlpbn, b0), bs_l, bq_l, Xbuf, accb, (l == 0) ? 1 : 0);
        #undef MK
    }
    mse_partial<<<dim3(3, 64), blk, 0, stream>>>(accb, msep);
    mse_final<<<1, 64, 0, stream>>>(msep, (float*)d_out);
}

// Round 11
// 1005.290 us; speedup vs baseline: 1.2583x; 1.1579x over previous
//
#include <hip/hip_runtime.h>
#include <hip/hip_bf16.h>
#include <stdint.h>

#define NN 4096
#define DD 256
#define NL 3
typedef unsigned int uint;
typedef unsigned short ushort_t;

typedef float f32x4 __attribute__((ext_vector_type(4)));
typedef short bf16x8 __attribute__((ext_vector_type(8)));

struct Ptrs4 { const float* p0; const float* p1; const float* p2; const float* p3; };
__device__ __forceinline__ const float* sel(const Ptrs4& p, int b) {
    return b == 0 ? p.p0 : b == 1 ? p.p1 : b == 2 ? p.p2 : p.p3;
}
struct Ptrs4U { const ushort_t* p0; const ushort_t* p1; const ushort_t* p2; const ushort_t* p3; };
__device__ __forceinline__ const ushort_t* selU(const Ptrs4U& p, int b) {
    return b == 0 ? p.p0 : b == 1 ? p.p1 : b == 2 ? p.p2 : p.p3;
}
struct PtrsW { const float* a0; const float* a1; const float* a2;
               const float* m0; const float* m1; const float* m2; };

// packed bf16 pair (RNE), low half = a, high half = b
__device__ __forceinline__ uint pkbf2(float a, float b) {
    __hip_bfloat162 t = __float22bfloat162_rn(float2{a, b});
    union { __hip_bfloat162 h; uint u; } c; c.h = t; return c.u;
}
// exact 3-way split of a pair: x = h + m + l + r, |r| <= ~2^-27 |x|
__device__ __forceinline__ void split3_pk(float a, float b, uint& h, uint& m, uint& l) {
    h = pkbf2(a, b);
    float ha = __uint_as_float(h << 16), hb = __uint_as_float(h & 0xFFFF0000u);
    float ra = a - ha, rb = b - hb;
    m = pkbf2(ra, rb);
    float ma = __uint_as_float(m << 16), mb = __uint_as_float(m & 0xFFFF0000u);
    l = pkbf2(ra - ma, rb - mb);
}

// async global->LDS; LDS dest = wave-uniform base + lane*size; global src per-lane
typedef __attribute__((address_space(3))) uint lds_u32;
typedef __attribute__((address_space(1))) const uint glb_u32;
__device__ __forceinline__ void gload16(void* l, const void* g) {
    __builtin_amdgcn_global_load_lds((glb_u32*)g, (lds_u32*)l, 16, 0, 0);
}
__device__ __forceinline__ void gload4(void* l, const void* g) {
    __builtin_amdgcn_global_load_lds((glb_u32*)g, (lds_u32*)l, 4, 0, 0);
}

// ---------------------------------------------------------------------------
// fp32 GEMM (R6-proven; retained for MODE 3 + fallback).
// ---------------------------------------------------------------------------
template<int MODE>
__global__ __launch_bounds__(256, 4)
void gemm_small(const float* __restrict__ Xin, Ptrs4 Wp, Ptrs4 bp,
                float* __restrict__ Out, float* __restrict__ cs, float* __restrict__ csq,
                ushort_t* __restrict__ Hso)
{
    const int b = blockIdx.z;
    const float* Wb = sel(Wp, b);
    const float* bb = sel(bp, b);
    const float* X = Xin + (size_t)b * NN * DD;
    float* O = Out + (size_t)b * NN * DD;
    ushort_t* HsO = Hso + (size_t)b * 3 * (size_t)DD * NN;
    const int row0 = blockIdx.y * 128, col0 = blockIdx.x * 64;
    const int tid = threadIdx.x;
    __shared__ float Asm[16][132];
    __shared__ float Bsm[16][68];
    const int tr = (tid >> 4) << 3, tc = (tid & 15) << 2;
    const int m = tid & 127, kk = (tid >> 7) << 3;
    const int bk = tid >> 4, bn = (tid & 15) << 2;
    const float* aSrc = X + (size_t)(row0 + m) * DD + kk;
    const float* bSrc = Wb + (size_t)bk * DD + col0 + bn;

    float acc[8][4] = {};
    float4 pa0 = *(const float4*)(aSrc);
    float4 pa1 = *(const float4*)(aSrc + 4);
    float4 pb  = *(const float4*)(bSrc);
    for (int t = 0; t < DD / 16; ++t) {
        Asm[kk+0][m]=pa0.x; Asm[kk+1][m]=pa0.y; Asm[kk+2][m]=pa0.z; Asm[kk+3][m]=pa0.w;
        Asm[kk+4][m]=pa1.x; Asm[kk+5][m]=pa1.y; Asm[kk+6][m]=pa1.z; Asm[kk+7][m]=pa1.w;
        *(float4*)&Bsm[bk][bn] = pb;
        __syncthreads();
        if (t < DD / 16 - 1) {
            const int k0 = (t + 1) * 16;
            pa0 = *(const float4*)(aSrc + k0);
            pa1 = *(const float4*)(aSrc + k0 + 4);
            pb  = *(const float4*)(bSrc + (size_t)k0 * DD);
        }
        #pragma unroll
        for (int k = 0; k < 16; ++k) {
            float a[8], bv[4];
            *(float4*)&a[0] = *(const float4*)&Asm[k][tr];
            *(float4*)&a[4] = *(const float4*)&Asm[k][tr + 4];
            *(float4*)&bv[0] = *(const float4*)&Bsm[k][tc];
            #pragma unroll
            for (int i = 0; i < 8; ++i)
                #pragma unroll
                for (int j = 0; j < 4; ++j)
                    acc[i][j] = fmaf(a[i], bv[j], acc[i][j]);
        }
        __syncthreads();
    }
    float bias4[4];
    *(float4*)bias4 = *(const float4*)(bb + col0 + tc);
    float s4[4] = {0.f,0.f,0.f,0.f}, q4[4] = {0.f,0.f,0.f,0.f};
    const int dph = col0 + tc;
    const size_t sb3 = (size_t)(dph >> 3) * (NN * 8) + (dph & 4);
    #pragma unroll
    for (int i = 0; i < 8; ++i) {
        float ov[4];
        #pragma unroll
        for (int j = 0; j < 4; ++j) {
            float v = acc[i][j] + bias4[j];
            if (MODE == 0 || MODE == 1 || MODE == 3) v = (v > 0.f) ? v : (expf(v) - 1.f);
            ov[j] = v;
            if (MODE == 1 || MODE == 3) s4[j] += v;
            if (MODE == 2) { s4[j] += v; q4[j] += v * v; }
        }
        if (MODE == 3) {
            uint2 vh, vm, vl;
            split3_pk(ov[0], ov[1], vh.x, vm.x, vl.x);
            split3_pk(ov[2], ov[3], vh.y, vm.y, vl.y);
            size_t off = sb3 + (size_t)(row0 + tr + i) * 8;
            *(uint2*)(HsO + off) = vh;
            *(uint2*)(HsO + (size_t)DD * NN + off) = vm;
            *(uint2*)(HsO + (size_t)2 * DD * NN + off) = vl;
        } else {
            float4 o; o.x = ov[0]; o.y = ov[1]; o.z = ov[2]; o.w = ov[3];
            *(float4*)(O + (size_t)(row0 + tr + i) * DD + col0 + tc) = o;
        }
    }
    if (MODE == 1 || MODE == 2 || MODE == 3) {
        __syncthreads();
        const int rg = tid >> 4;
        #pragma unroll
        for (int j = 0; j < 4; ++j) {
            Asm[rg][tc + j] = s4[j];
            if (MODE == 2) Bsm[rg][tc + j] = q4[j];
        }
        __syncthreads();
        if (tid < 64) {
            float s = 0.f, q = 0.f;
            #pragma unroll
            for (int r = 0; r < 16; ++r) { s += Asm[r][tid]; if (MODE == 2) q += Bsm[r][tid]; }
            atomicAdd(&cs[b * DD + col0 + tid], s);
            if (MODE == 2) atomicAdd(&csq[b * DD + col0 + tid], q);
        }
    }
}

// ---------------------------------------------------------------------------
// weight pre-split: W[k][col] fp32 -> Wsp[z][lvl][col][k] bf16 3-split.
// z<6: adjW[z>>1] matrix (z&1); z>=6: mlpW[(z-6)/6] matrix ((z-6)%6).
// ---------------------------------------------------------------------------
__global__ __launch_bounds__(256)
void wsplitk(PtrsW W, ushort_t* __restrict__ Wsp)
{
    const int z = blockIdx.z;
    const float* src;
    if (z < 6) {
        const float* base = (z >> 1) == 0 ? W.a0 : (z >> 1) == 1 ? W.a1 : W.a2;
        src = base + (size_t)(z & 1) * DD * DD;
    } else {
        int zz = z - 6;
        const float* base = (zz / 6) == 0 ? W.m0 : (zz / 6) == 1 ? W.m1 : W.m2;
        src = base + (size_t)(zz % 6) * DD * DD;
    }
    ushort_t* dst = Wsp + (size_t)z * 3 * DD * DD;
    const int k0 = blockIdx.x * 64, c0 = blockIdx.y * 64;
    __shared__ float ls[64][65];
    const int tid = threadIdx.x;
    #pragma unroll
    for (int i = 0; i < 4; ++i) {
        int u = (i << 8) + tid;
        int r = u >> 4, c4 = (u & 15) << 2;
        float4 v = *(const float4*)(src + (size_t)(k0 + r) * DD + c0 + c4);
        ls[r][c4] = v.x; ls[r][c4+1] = v.y; ls[r][c4+2] = v.z; ls[r][c4+3] = v.w;
    }
    __syncthreads();
    const int col = tid >> 2, seg = (tid & 3) << 4;
    uint ph[8], pm[8], pl[8];
    #pragma unroll
    for (int jj = 0; jj < 8; ++jj) {
        float a = ls[seg + 2 * jj][col];
        float c = ls[seg + 2 * jj + 1][col];
        split3_pk(a, c, ph[jj], pm[jj], pl[jj]);
    }
    size_t idx = (size_t)(c0 + col) * DD + k0 + seg;
    #pragma unroll
    for (int lvl = 0; lvl < 3; ++lvl) {
        uint* pp = lvl == 0 ? ph : lvl == 1 ? pm : pl;
        *(uint4*)(dst + (size_t)lvl * DD * DD + idx)     = *(uint4*)&pp[0];
        *(uint4*)(dst + (size_t)lvl * DD * DD + idx + 8) = *(uint4*)&pp[4];
    }
}

// ---------------------------------------------------------------------------
// split-bf16 MFMA GEMM: Out = act(X @ W + b), W pre-split [lvl][col][k].
// Structure: R6 2-barrier reg-prefetch (A) + masked-style DMA dbuf (B) with
// both-sides XOR slot swizzle. C layout copied from masked's proven writer.
// MODE 0: elu; MODE 2: linear + BN stats.
// ---------------------------------------------------------------------------
template<int MODE>
__global__ void gemm_mfma(const float* __restrict__ Xin, Ptrs4U Wsp, Ptrs4 bp,
                          float* __restrict__ Out, float* __restrict__ cs,
                          float* __restrict__ csq)
{
    const int b = blockIdx.z;
    const ushort_t* Wb = selU(Wsp, b);
    const float* bb = sel(bp, b);
    const float* X = Xin + (size_t)b * NN * DD;
    float* O = Out + (size_t)b * NN * DD;
    const int row0 = blockIdx.y * 128, col0 = blockIdx.x * 64;
    const int tid = threadIdx.x;
    const int wave = tid >> 6, ln = tid & 15, quad = (tid >> 4) & 3;
    const int wrow = wave >> 1, wcol = wave & 1;
    __shared__ ushort_t As[3][128][32];     // 24 KB, slot-swizzled
    __shared__ ushort_t Bs[2][3][64][32];   // 24 KB, DMA dbuf

    // A staging geometry: thread covers (arow, 16 k); slot = kquad ^ ((arow>>1)&3)
    const int arow = tid >> 1, kb16 = (tid & 1) << 4;
    const int xr = (arow >> 1) & 3;
    const int s0 = (((kb16 >> 3) + 0) ^ xr) << 3;
    const int s1 = (((kb16 >> 3) + 1) ^ xr) << 3;
    const float* aSrc = X + (size_t)(row0 + arow) * DD + kb16;

    // B DMA: col c=tid>>2, pre-swizzled source chunk qp
    const int qp = (tid & 3) ^ ((tid >> 3) & 3);
    const size_t bgoff = (size_t)(col0 + (tid >> 2)) * DD + (size_t)qp * 8;

    #define BSTAGE(buf, t_) { \
        _Pragma("unroll") \
        for (int lvl = 0; lvl < 3; ++lvl) \
            gload16((char*)&Bs[buf][lvl][0][0] + (wave << 10), \
                    Wb + (size_t)lvl * DD * DD + bgoff + (size_t)(t_) * 32); }

    f32x4 acc[4][2] = {};
    float4 pa0 = *(const float4*)(aSrc),     pa1 = *(const float4*)(aSrc + 4);
    float4 pa2 = *(const float4*)(aSrc + 8), pa3 = *(const float4*)(aSrc + 12);
    BSTAGE(0, 0)
    for (int t = 0; t < DD / 32; ++t) {
        {   // split + swizzled LDS write (values from prefetch regs)
            uint hh[8], mm[8], ll[8];
            split3_pk(pa0.x, pa0.y, hh[0], mm[0], ll[0]);
            split3_pk(pa0.z, pa0.w, hh[1], mm[1], ll[1]);
            split3_pk(pa1.x, pa1.y, hh[2], mm[2], ll[2]);
            split3_pk(pa1.z, pa1.w, hh[3], mm[3], ll[3]);
            split3_pk(pa2.x, pa2.y, hh[4], mm[4], ll[4]);
            split3_pk(pa2.z, pa2.w, hh[5], mm[5], ll[5]);
            split3_pk(pa3.x, pa3.y, hh[6], mm[6], ll[6]);
            split3_pk(pa3.z, pa3.w, hh[7], mm[7], ll[7]);
            uint4 v;
            v.x=hh[0]; v.y=hh[1]; v.z=hh[2]; v.w=hh[3]; *(uint4*)&As[0][arow][s0] = v;
            v.x=hh[4]; v.y=hh[5]; v.z=hh[6]; v.w=hh[7]; *(uint4*)&As[0][arow][s1] = v;
            v.x=mm[0]; v.y=mm[1]; v.z=mm[2]; v.w=mm[3]; *(uint4*)&As[1][arow][s0] = v;
            v.x=mm[4]; v.y=mm[5]; v.z=mm[6]; v.w=mm[7]; *(uint4*)&As[1][arow][s1] = v;
            v.x=ll[0]; v.y=ll[1]; v.z=ll[2]; v.w=ll[3]; *(uint4*)&As[2][arow][s0] = v;
            v.x=ll[4]; v.y=ll[5]; v.z=ll[6]; v.w=ll[7]; *(uint4*)&As[2][arow][s1] = v;
        }
        __syncthreads();   // drains B DMA for tile t, publishes As
        if (t < DD / 32 - 1) {
            const float* an = aSrc + (t + 1) * 32;
            pa0 = *(const float4*)(an);     pa1 = *(const float4*)(an + 4);
            pa2 = *(const float4*)(an + 8); pa3 = *(const float4*)(an + 12);
            BSTAGE((t + 1) & 1, t + 1)
        }
        bf16x8 af[4][3];
        #pragma unroll
        for (int mt = 0; mt < 4; ++mt) {
            const int row = wrow * 64 + mt * 16 + ln;
            const int sl = ((quad ^ ((row >> 1) & 3)) << 3);
            #pragma unroll
            for (int lvl = 0; lvl < 3; ++lvl)
                af[mt][lvl] = *(const bf16x8*)&As[lvl][row][sl];
        }
        const int cur = t & 1;
        #pragma unroll
        for (int nt = 0; nt < 2; ++nt) {
            const int n = wcol * 32 + nt * 16 + ln;
            const int slot = ((quad ^ ((n >> 1) & 3)) << 3);
            bf16x8 bh = *(const bf16x8*)&Bs[cur][0][n][slot];
            bf16x8 bm = *(const bf16x8*)&Bs[cur][1][n][slot];
            bf16x8 bl = *(const bf16x8*)&Bs[cur][2][n][slot];
            #pragma unroll
            for (int mt = 0; mt < 4; ++mt) {
                f32x4 a = acc[mt][nt];
                a = __builtin_amdgcn_mfma_f32_16x16x32_bf16(af[mt][0], bh, a, 0, 0, 0);
                a = __builtin_amdgcn_mfma_f32_16x16x32_bf16(af[mt][0], bm, a, 0, 0, 0);
                a = __builtin_amdgcn_mfma_f32_16x16x32_bf16(af[mt][1], bh, a, 0, 0, 0);
                a = __builtin_amdgcn_mfma_f32_16x16x32_bf16(af[mt][0], bl, a, 0, 0, 0);
                a = __builtin_amdgcn_mfma_f32_16x16x32_bf16(af[mt][2], bh, a, 0, 0, 0);
                a = __builtin_amdgcn_mfma_f32_16x16x32_bf16(af[mt][1], bm, a, 0, 0, 0);
                acc[mt][nt] = a;
            }
        }
        __syncthreads();
    }
    #undef BSTAGE

    // epilogue: C layout = masked's proven mapping
    float bcol[2], ssum[2] = {0.f, 0.f}, qsum[2] = {0.f, 0.f};
    #pragma unroll
    for (int nt = 0; nt < 2; ++nt) bcol[nt] = bb[col0 + wcol * 32 + nt * 16 + ln];
    #pragma unroll
    for (int mt = 0; mt < 4; ++mt)
        #pragma unroll
        for (int nt = 0; nt < 2; ++nt)
            #pragma unroll
            for (int r = 0; r < 4; ++r) {
                int row = row0 + wrow * 64 + mt * 16 + quad * 4 + r;
                int col = col0 + wcol * 32 + nt * 16 + ln;
                float v = acc[mt][nt][r] + bcol[nt];
                if (MODE == 0) v = (v > 0.f) ? v : (expf(v) - 1.f);
                if (MODE == 2) { ssum[nt] += v; qsum[nt] += v * v; }
                O[(size_t)row * DD + col] = v;
            }
    if (MODE == 2) {
        float* scrS = (float*)&As[0][0][0];   // [8][64]
        float* scrQ = scrS + 512;             // [8][64]
        const int rg = wrow * 4 + quad;       // 0..7
        #pragma unroll
        for (int nt = 0; nt < 2; ++nt) {
            const int cl = wcol * 32 + nt * 16 + ln;
            scrS[rg * 64 + cl] = ssum[nt];
            scrQ[rg * 64 + cl] = qsum[nt];
        }
        __syncthreads();
        if (tid < 64) {
            float s = 0.f, q = 0.f;
            #pragma unroll
            for (int r = 0; r < 8; ++r) { s += scrS[r * 64 + tid]; q += scrQ[r * 64 + tid]; }
            atomicAdd(&cs[b * DD + col0 + tid], s);
            atomicAdd(&csq[b * DD + col0 + tid], q);
        }
    }
}

// ---------------------------------------------------------------------------
// split-bf16 MFMA version of gemm_bnrelu: X = relu(bn(G)) @ W + b; acc += X.
// BN+relu applied at A-staging (before split), W pre-split.
// ---------------------------------------------------------------------------
__global__ void gemm_bnrelu_m(const float* __restrict__ G, Ptrs4U Wsp, Ptrs4 bp, Ptrs4 gbp,
                              const float* __restrict__ bns, const float* __restrict__ bnq,
                              float* __restrict__ Xout, float* __restrict__ accb, int first)
{
    const int b = blockIdx.z;
    const ushort_t* Wb = selU(Wsp, b);
    const float* bb = sel(bp, b);
    const float* gb = sel(gbp, b);
    const float* Gb = G + (size_t)b * NN * DD;
    float* O = Xout + (size_t)b * NN * DD;
    float* Ab = accb + (size_t)b * NN * DD;
    const int row0 = blockIdx.y * 128, col0 = blockIdx.x * 64;
    const int tid = threadIdx.x;
    const int wave = tid >> 6, ln = tid & 15, quad = (tid >> 4) & 3;
    const int wrow = wave >> 1, wcol = wave & 1;
    __shared__ ushort_t As[3][128][32];
    __shared__ ushort_t Bs[2][3][64][32];
    __shared__ float scs[DD], shs[DD];
    {
        float mu = bns[b * DD + tid] * (1.0f / NN);
        float ms = bnq[b * DD + tid] * (1.0f / NN);
        float var = ms - mu * mu;
        float sc = gb[tid] / sqrtf(var + 1e-5f);
        scs[tid] = sc;
        shs[tid] = gb[DD + tid] - mu * sc;
    }

    const int arow = tid >> 1, kb16 = (tid & 1) << 4;
    const int xr = (arow >> 1) & 3;
    const int s0 = (((kb16 >> 3) + 0) ^ xr) << 3;
    const int s1 = (((kb16 >> 3) + 1) ^ xr) << 3;
    const float* aSrc = Gb + (size_t)(row0 + arow) * DD + kb16;

    const int qp = (tid & 3) ^ ((tid >> 3) & 3);
    const size_t bgoff = (size_t)(col0 + (tid >> 2)) * DD + (size_t)qp * 8;

    #define BSTAGE(buf, t_) { \
        _Pragma("unroll") \
        for (int lvl = 0; lvl < 3; ++lvl) \
            gload16((char*)&Bs[buf][lvl][0][0] + (wave << 10), \
                    Wb + (size_t)lvl * DD * DD + bgoff + (size_t)(t_) * 32); }

    f32x4 acc[4][2] = {};
    float4 pa0 = *(const float4*)(aSrc),     pa1 = *(const float4*)(aSrc + 4);
    float4 pa2 = *(const float4*)(aSrc + 8), pa3 = *(const float4*)(aSrc + 12);
    BSTAGE(0, 0)
    __syncthreads();   // publish scs/shs before first use
    for (int t = 0; t < DD / 32; ++t) {
        {
            const int kg = t * 32 + kb16;
            float f[16] = {pa0.x,pa0.y,pa0.z,pa0.w, pa1.x,pa1.y,pa1.z,pa1.w,
                           pa2.x,pa2.y,pa2.z,pa2.w, pa3.x,pa3.y,pa3.z,pa3.w};
            #pragma unroll
            for (int i = 0; i < 16; ++i) {
                float v = fmaf(f[i], scs[kg + i], shs[kg + i]);
                f[i] = v > 0.f ? v : 0.f;
            }
            uint hh[8], mm[8], ll[8];
            #pragma unroll
            for (int p = 0; p < 8; ++p)
                split3_pk(f[2 * p], f[2 * p + 1], hh[p], mm[p], ll[p]);
            uint4 v;
            v.x=hh[0]; v.y=hh[1]; v.z=hh[2]; v.w=hh[3]; *(uint4*)&As[0][arow][s0] = v;
            v.x=hh[4]; v.y=hh[5]; v.z=hh[6]; v.w=hh[7]; *(uint4*)&As[0][arow][s1] = v;
            v.x=mm[0]; v.y=mm[1]; v.z=mm[2]; v.w=mm[3]; *(uint4*)&As[1][arow][s0] = v;
            v.x=mm[4]; v.y=mm[5]; v.z=mm[6]; v.w=mm[7]; *(uint4*)&As[1][arow][s1] = v;
            v.x=ll[0]; v.y=ll[1]; v.z=ll[2]; v.w=ll[3]; *(uint4*)&As[2][arow][s0] = v;
            v.x=ll[4]; v.y=ll[5]; v.z=ll[6]; v.w=ll[7]; *(uint4*)&As[2][arow][s1] = v;
        }
        __syncthreads();
        if (t < DD / 32 - 1) {
            const float* an = aSrc + (t + 1) * 32;
            pa0 = *(const float4*)(an);     pa1 = *(const float4*)(an + 4);
            pa2 = *(const float4*)(an + 8); pa3 = *(const float4*)(an + 12);
            BSTAGE((t + 1) & 1, t + 1)
        }
        bf16x8 af[4][3];
        #pragma unroll
        for (int mt = 0; mt < 4; ++mt) {
            const int row = wrow * 64 + mt * 16 + ln;
            const int sl = ((quad ^ ((row >> 1) & 3)) << 3);
            #pragma unroll
            for (int lvl = 0; lvl < 3; ++lvl)
                af[mt][lvl] = *(const bf16x8*)&As[lvl][row][sl];
        }
        const int cur = t & 1;
        #pragma unroll
        for (int nt = 0; nt < 2; ++nt) {
            const int n = wcol * 32 + nt * 16 + ln;
            const int slot = ((quad ^ ((n >> 1) & 3)) << 3);
            bf16x8 bh = *(const bf16x8*)&Bs[cur][0][n][slot];
            bf16x8 bm = *(const bf16x8*)&Bs[cur][1][n][slot];
            bf16x8 bl = *(const bf16x8*)&Bs[cur][2][n][slot];
            #pragma unroll
            for (int mt = 0; mt < 4; ++mt) {
                f32x4 a = acc[mt][nt];
                a = __builtin_amdgcn_mfma_f32_16x16x32_bf16(af[mt][0], bh, a, 0, 0, 0);
                a = __builtin_amdgcn_mfma_f32_16x16x32_bf16(af[mt][0], bm, a, 0, 0, 0);
                a = __builtin_amdgcn_mfma_f32_16x16x32_bf16(af[mt][1], bh, a, 0, 0, 0);
                a = __builtin_amdgcn_mfma_f32_16x16x32_bf16(af[mt][0], bl, a, 0, 0, 0);
                a = __builtin_amdgcn_mfma_f32_16x16x32_bf16(af[mt][2], bh, a, 0, 0, 0);
                a = __builtin_amdgcn_mfma_f32_16x16x32_bf16(af[mt][1], bm, a, 0, 0, 0);
                acc[mt][nt] = a;
            }
        }
        __syncthreads();
    }
    #undef BSTAGE

    float bcol[2];
    #pragma unroll
    for (int nt = 0; nt < 2; ++nt) bcol[nt] = bb[col0 + wcol * 32 + nt * 16 + ln];
    #pragma unroll
    for (int mt = 0; mt < 4; ++mt)
        #pragma unroll
        for (int nt = 0; nt < 2; ++nt)
            #pragma unroll
            for (int r = 0; r < 4; ++r) {
                int row = row0 + wrow * 64 + mt * 16 + quad * 4 + r;
                int col = col0 + wcol * 32 + nt * 16 + ln;
                size_t idx = (size_t)row * DD + col;
                float v = acc[mt][nt][r] + bcol[nt];
                O[idx] = v;
                if (first) Ab[idx] = v;
                else       Ab[idx] = Ab[idx] + v;
            }
}

// threshold per branch: t = ||colsum||^2 / N^2
__global__ void thresh_k(const float* __restrict__ cs, float* __restrict__ tvals)
{
    const int b = blockIdx.x, t = threadIdx.x;
    __shared__ float red[256];
    float v = cs[b * DD + t];
    red[t] = v * v;
    __syncthreads();
    for (int s = 128; s > 0; s >>= 1) { if (t < s) red[t] += red[t + s]; __syncthreads(); }
    if (t == 0) tvals[b] = red[0] * (1.0f / 16777216.0f);
}

// ---------------------------------------------------------------------------
// transpose + exact 3-split: X[b][n][d] fp32 -> S{h,m,l}[b][d][j=n] bf16.
// ---------------------------------------------------------------------------
__global__ __launch_bounds__(256)
void tsplit_x(const float* __restrict__ Xin, ushort_t* __restrict__ Sh,
              ushort_t* __restrict__ Sm, ushort_t* __restrict__ Sl)
{
    const int b = blockIdx.z;
    const int n0 = blockIdx.x * 64, d0 = blockIdx.y * 64;
    const float* X = Xin + (size_t)b * NN * DD;
    __shared__ float ls[64][65];
    const int tid = threadIdx.x;
    #pragma unroll
    for (int i = 0; i < 4; ++i) {
        int u = (i << 8) + tid;
        int r = u >> 4, c4 = (u & 15) << 2;
        float4 v = *(const float4*)(X + (size_t)(n0 + r) * DD + d0 + c4);
        ls[r][c4] = v.x; ls[r][c4+1] = v.y; ls[r][c4+2] = v.z; ls[r][c4+3] = v.w;
    }
    __syncthreads();
    const int d = tid >> 2, seg = (tid & 3) << 4;
    uint ph[8], pm[8], pl[8];
    #pragma unroll
    for (int jj = 0; jj < 8; ++jj) {
        float a = ls[seg + 2 * jj][d];
        float c = ls[seg + 2 * jj + 1][d];
        split3_pk(a, c, ph[jj], pm[jj], pl[jj]);
    }
    size_t idx = ((size_t)(b * DD + d0 + d)) * NN + n0 + seg;
    *(uint4*)(Sh + idx)     = *(uint4*)&ph[0];
    *(uint4*)(Sh + idx + 8) = *(uint4*)&ph[4];
    *(uint4*)(Sm + idx)     = *(uint4*)&pm[0];
    *(uint4*)(Sm + idx + 8) = *(uint4*)&pm[4];
    *(uint4*)(Sl + idx)     = *(uint4*)&pl[0];
    *(uint4*)(Sl + idx + 8) = *(uint4*)&pl[4];
}

// ---------------------------------------------------------------------------
// adj v1 (fallback, proven): fp32 staging + in-tile split.
// ---------------------------------------------------------------------------
__global__ __launch_bounds__(256, 3)
void adj_mfma_s(const float* __restrict__ H, const float* __restrict__ tvals,
                uint8_t* __restrict__ mask)
{
    int t = blockIdx.x;
    int by = 0, rem = 32;
    while (t >= rem) { t -= rem; rem--; by++; }
    const int bx = by + t;
    const int b = blockIdx.z;
    const int row0 = by * 128, col0 = bx * 128;
    const int tid = threadIdx.x;
    const int wave = tid >> 6, ln = tid & 15, quad = (tid >> 4) & 3;
    const int wrow = wave >> 1, wcol = wave & 1;
    const float* Hb = H + (size_t)b * NN * DD;
    uint8_t* Mb = mask + (size_t)b * NN * (NN / 8);
    __shared__ ushort_t hs[2][3][128][34];

    f32x4 acc[4][4] = {};
    for (int k0 = 0; k0 < DD; k0 += 32) {
        #pragma unroll
        for (int i = 0; i < 8; ++i) {
            int f = (i << 8) + tid;
            int sr = f >> 3;
            int side = sr >> 7, r = sr & 127, part = f & 7;
            int grow = (side ? col0 : row0) + r;
            float4 v = *(const float4*)(Hb + (size_t)grow * DD + k0 + part * 4);
            uint h0, m0, l0, h1, m1, l1;
            split3_pk(v.x, v.y, h0, m0, l0);
            split3_pk(v.z, v.w, h1, m1, l1);
            uint2 ph; ph.x = h0; ph.y = h1;
            uint2 pm; pm.x = m0; pm.y = m1;
            uint2 pl; pl.x = l0; pl.y = l1;
            *(uint2*)&hs[side][0][r][part * 4] = ph;
            *(uint2*)&hs[side][1][r][part * 4] = pm;
            *(uint2*)&hs[side][2][r][part * 4] = pl;
        }
        __syncthreads();
        bf16x8 af[4][3];
        #pragma unroll
        for (int mt = 0; mt < 4; ++mt)
            #pragma unroll
            for (int lvl = 0; lvl < 3; ++lvl)
                af[mt][lvl] = *(const bf16x8*)&hs[0][lvl][wrow * 64 + mt * 16 + ln][quad * 8];
        #pragma unroll
        for (int nt = 0; nt < 4; ++nt) {
            int n = wcol * 64 + nt * 16 + ln;
            bf16x8 bh = *(const bf16x8*)&hs[1][0][n][quad * 8];
            bf16x8 bm = *(const bf16x8*)&hs[1][1][n][quad * 8];
            bf16x8 bl = *(const bf16x8*)&hs[1][2][n][quad * 8];
            #pragma unroll
            for (int mt = 0; mt < 4; ++mt) {
                f32x4 a = acc[mt][nt];
                a = __builtin_amdgcn_mfma_f32_16x16x32_bf16(af[mt][0], bh, a, 0, 0, 0);
                a = __builtin_amdgcn_mfma_f32_16x16x32_bf16(af[mt][0], bm, a, 0, 0, 0);
                a = __builtin_amdgcn_mfma_f32_16x16x32_bf16(af[mt][1], bh, a, 0, 0, 0);
                a = __builtin_amdgcn_mfma_f32_16x16x32_bf16(af[mt][0], bl, a, 0, 0, 0);
                a = __builtin_amdgcn_mfma_f32_16x16x32_bf16(af[mt][2], bh, a, 0, 0, 0);
                a = __builtin_amdgcn_mfma_f32_16x16x32_bf16(af[mt][1], bm, a, 0, 0, 0);
                acc[mt][nt] = a;
            }
        }
        __syncthreads();
    }
    const float t2 = tvals[b];
    #pragma unroll
    for (int mt = 0; mt < 4; ++mt)
        #pragma unroll
        for (int nt = 0; nt < 4; ++nt) {
            bool p0 = acc[mt][nt][0] > t2, p1 = acc[mt][nt][1] > t2;
            bool p2 = acc[mt][nt][2] > t2, p3 = acc[mt][nt][3] > t2;
            unsigned long long bal[4];
            bal[0] = __ballot(p0); bal[1] = __ballot(p1);
            bal[2] = __ballot(p2); bal[3] = __ballot(p3);
            if ((tid & 63) < 16) {
                int q = ln >> 2, rsel = ln & 3;
                unsigned long long bv = rsel == 0 ? bal[0] : rsel == 1 ? bal[1]
                                       : rsel == 2 ? bal[2] : bal[3];
                ushort_t u16 = (ushort_t)((bv >> (q * 16)) & 0xFFFFull);
                int row = row0 + wrow * 64 + mt * 16 + ln;
                int colb = (col0 + wcol * 64 + nt * 16) >> 3;
                *(ushort_t*)(Mb + (size_t)row * (NN / 8) + colb) = u16;
            }
            uint nib = (p0 ? 1u : 0u) | (p1 ? 2u : 0u) | (p2 ? 4u : 0u) | (p3 ? 8u : 0u);
            uint other = (uint)__shfl_xor((int)nib, 16);
            if ((quad & 1) == 0) {
                uint byt = nib | (other << 4);
                int rowm = col0 + wcol * 64 + nt * 16 + ln;
                int colbm = ((row0 + wrow * 64 + mt * 16) >> 3) + (quad >> 1);
                Mb[(size_t)rowm * (NN / 8) + colbm] = (uint8_t)byt;
            }
        }
}

// ---------------------------------------------------------------------------
// adj v2 (fast path): pure bf16 MFMA from precomputed splits. (R0-proven DMA)
// ---------------------------------------------------------------------------
__global__ __launch_bounds__(256, 3)
void adj_mfma_v2(const ushort_t* __restrict__ Hs, const float* __restrict__ tvals,
                 uint8_t* __restrict__ mask)
{
    int t = blockIdx.x;
    int by = 0, rem = 32;
    while (t >= rem) { t -= rem; rem--; by++; }
    const int bx = by + t;
    const int b = blockIdx.z;
    const int row0 = by * 128, col0 = bx * 128;
    const int tid = threadIdx.x;
    const int wave = tid >> 6, ln = tid & 15, quad = (tid >> 4) & 3;
    const int wrow = wave >> 1, wcol = wave & 1;
    const ushort_t* Hb = Hs + (size_t)b * 3 * (size_t)DD * NN;
    uint8_t* Mb = mask + (size_t)b * NN * (NN / 8);
    __shared__ ushort_t hs2[6][4][128][8];

    const int grow = tid & 127;
    const int qb = tid >> 7;
    const size_t var0 = (size_t)qb * (NN * 8) + (size_t)(row0 + grow) * 8;
    const size_t var1 = (size_t)qb * (NN * 8) + (size_t)(col0 + grow) * 8;

    f32x4 acc[4][4] = {};
    for (int kb0 = 0; kb0 < DD / 8; kb0 += 4) {
        #pragma unroll
        for (int c = 0; c < 12; ++c) {
            const int sl = c >> 1, part = c & 1;
            const int side = sl / 3, lvl = sl % 3;
            const ushort_t* g = Hb + (size_t)lvl * DD * NN
                                   + (size_t)(kb0 + part * 2) * (NN * 8)
                                   + (side ? var1 : var0);
            char* l = (char*)&hs2[0][0][0][0] + (((sl * 8 + part * 4 + wave)) << 10);
            gload16(l, g);
        }
        __syncthreads();
        bf16x8 af[4][3];
        #pragma unroll
        for (int mt = 0; mt < 4; ++mt)
            #pragma unroll
            for (int lvl = 0; lvl < 3; ++lvl)
                af[mt][lvl] = *(const bf16x8*)&hs2[lvl][quad][wrow * 64 + mt * 16 + ln][0];
        #pragma unroll
        for (int nt = 0; nt < 4; ++nt) {
            const int n = wcol * 64 + nt * 16 + ln;
            bf16x8 bh = *(const bf16x8*)&hs2[3][quad][n][0];
            bf16x8 bm = *(const bf16x8*)&hs2[4][quad][n][0];
            bf16x8 bl = *(const bf16x8*)&hs2[5][quad][n][0];
            #pragma unroll
            for (int mt = 0; mt < 4; ++mt) {
                f32x4 a = acc[mt][nt];
                a = __builtin_amdgcn_mfma_f32_16x16x32_bf16(af[mt][0], bh, a, 0, 0, 0);
                a = __builtin_amdgcn_mfma_f32_16x16x32_bf16(af[mt][0], bm, a, 0, 0, 0);
                a = __builtin_amdgcn_mfma_f32_16x16x32_bf16(af[mt][1], bh, a, 0, 0, 0);
                a = __builtin_amdgcn_mfma_f32_16x16x32_bf16(af[mt][0], bl, a, 0, 0, 0);
                a = __builtin_amdgcn_mfma_f32_16x16x32_bf16(af[mt][2], bh, a, 0, 0, 0);
                a = __builtin_amdgcn_mfma_f32_16x16x32_bf16(af[mt][1], bm, a, 0, 0, 0);
                acc[mt][nt] = a;
            }
        }
        __syncthreads();
    }
    const float t2 = tvals[b];
    #pragma unroll
    for (int mt = 0; mt < 4; ++mt)
        #pragma unroll
        for (int nt = 0; nt < 4; ++nt) {
            bool p0 = acc[mt][nt][0] > t2, p1 = acc[mt][nt][1] > t2;
            bool p2 = acc[mt][nt][2] > t2, p3 = acc[mt][nt][3] > t2;
            unsigned long long bal[4];
            bal[0] = __ballot(p0); bal[1] = __ballot(p1);
            bal[2] = __ballot(p2); bal[3] = __ballot(p3);
            if ((tid & 63) < 16) {
                int q = ln >> 2, rsel = ln & 3;
                unsigned long long bv = rsel == 0 ? bal[0] : rsel == 1 ? bal[1]
                                       : rsel == 2 ? bal[2] : bal[3];
                ushort_t u16 = (ushort_t)((bv >> (q * 16)) & 0xFFFFull);
                int row = row0 + wrow * 64 + mt * 16 + ln;
                int colb = (col0 + wcol * 64 + nt * 16) >> 3;
                *(ushort_t*)(Mb + (size_t)row * (NN / 8) + colb) = u16;
            }
            uint nib = (p0 ? 1u : 0u) | (p1 ? 2u : 0u) | (p2 ? 4u : 0u) | (p3 ? 8u : 0u);
            uint other = (uint)__shfl_xor((int)nib, 16);
            if ((quad & 1) == 0) {
                uint byt = nib | (other << 4);
                int rowm = col0 + wcol * 64 + nt * 16 + ln;
                int colbm = ((row0 + wrow * 64 + mt * 16) >> 3) + (quad >> 1);
                Mb[(size_t)rowm * (NN / 8) + colbm] = (uint8_t)byt;
            }
        }
}

// ---------------------------------------------------------------------------
// X' = X + M @ X via MFMA, IN-PLACE into X.  (R3 DMA dbuf + XOR swz + R7 LUT)
// ---------------------------------------------------------------------------
__global__ __launch_bounds__(256)
void masked_mfma(float* __restrict__ Xio, const ushort_t* __restrict__ Sh,
                 const ushort_t* __restrict__ Sm, const ushort_t* __restrict__ Sl,
                 const uint8_t* __restrict__ mask)
{
    const int b = blockIdx.z;
    const int row0 = blockIdx.y * 128, col0 = blockIdx.x * 64;
    const int tid = threadIdx.x;
    const int wave = tid >> 6, ln = tid & 15, quad = (tid >> 4) & 3;
    const int wrow = wave >> 1, wcol = wave & 1;
    float* X = Xio + (size_t)b * NN * DD;
    const size_t sb = (size_t)b * DD * NN;
    const ushort_t* Ss[3] = { Sh + sb, Sm + sb, Sl + sb };
    const uint* Mw = (const uint*)(mask + (size_t)b * NN * (NN / 8));
    __shared__ ushort_t bt2[2][3][2][64][32];
    __shared__ uint msk2[2][2][128];
    __shared__ uint lut[256][4];

    #pragma unroll
    for (int p = 0; p < 4; ++p)
        lut[tid][p] = (((tid >> (2 * p)) & 1u) ? 0x3F80u : 0u) |
                      (((tid >> (2 * p + 1)) & 1u) ? 0x3F800000u : 0u);

    const int c = tid >> 2;
    const int qp = (tid & 3) ^ ((tid >> 3) & 3);
    const size_t goff = (size_t)(col0 + c) * NN + (size_t)qp * 8;
    const size_t mrow = (size_t)(row0 + (tid & 127)) * 128;

    f32x4 acc[4][2] = {};

    #define STAGE(buf, t)                                                         \
        {                                                                         \
            const size_t j_ = (size_t)(t) * 64;                                   \
            _Pragma("unroll")                                                     \
            for (int lvl = 0; lvl < 3; ++lvl) {                                   \
                gload16((char*)&bt2[buf][lvl][0][0][0] + (wave << 10),            \
                        Ss[lvl] + goff + j_);                                     \
                gload16((char*)&bt2[buf][lvl][1][0][0] + (wave << 10),            \
                        Ss[lvl] + goff + j_ + 32);                                \
            }                                                                     \
            if (tid < 128) {                                                      \
                gload4((char*)&msk2[buf][0][0] + (wave << 8), Mw + mrow + 2*(t)); \
                gload4((char*)&msk2[buf][1][0] + (wave << 8), Mw + mrow + 2*(t)+1);\
            }                                                                     \
        }

    STAGE(0, 0);
    __syncthreads();

    for (int t = 0; t < NN / 64; ++t) {
        const int cur = t & 1;
        if (t < NN / 64 - 1) STAGE(cur ^ 1, t + 1);
        #pragma unroll
        for (int kk = 0; kk < 2; ++kk) {
            bf16x8 afr[4];
            #pragma unroll
            for (int mt = 0; mt < 4; ++mt) {
                uint w = msk2[cur][kk][wrow * 64 + mt * 16 + ln];
                uint byte = (w >> (quad * 8)) & 0xFFu;
                afr[mt] = *(const bf16x8*)&lut[byte][0];
            }
            #pragma unroll
            for (int nt = 0; nt < 2; ++nt) {
                const int n = wcol * 32 + nt * 16 + ln;
                const int slot = (quad ^ ((n >> 1) & 3)) * 8;
                bf16x8 bh = *(const bf16x8*)&bt2[cur][0][kk][n][slot];
                bf16x8 bm = *(const bf16x8*)&bt2[cur][1][kk][n][slot];
                bf16x8 bl = *(const bf16x8*)&bt2[cur][2][kk][n][slot];
                #pragma unroll
                for (int mt = 0; mt < 4; ++mt) {
                    f32x4 a = acc[mt][nt];
                    a = __builtin_amdgcn_mfma_f32_16x16x32_bf16(afr[mt], bh, a, 0, 0, 0);
                    a = __builtin_amdgcn_mfma_f32_16x16x32_bf16(afr[mt], bm, a, 0, 0, 0);
                    a = __builtin_amdgcn_mfma_f32_16x16x32_bf16(afr[mt], bl, a, 0, 0, 0);
                    acc[mt][nt] = a;
                }
            }
        }
        __syncthreads();
    }
    #undef STAGE
    #pragma unroll
    for (int mt = 0; mt < 4; ++mt)
        #pragma unroll
        for (int nt = 0; nt < 2; ++nt)
            #pragma unroll
            for (int r = 0; r < 4; ++r) {
                int row = row0 + wrow * 64 + mt * 16 + quad * 4 + r;
                int col = col0 + wcol * 32 + nt * 16 + ln;
                size_t idx = (size_t)row * DD + col;
                X[idx] = X[idx] + acc[mt][nt][r];
            }
}

// ---------------------------------------------------------------------------
// X = relu(bn(G)) @ W + bias;  acc (+)= X.  (R6-proven fp32, fallback)
// ---------------------------------------------------------------------------
__global__ __launch_bounds__(256, 4)
void gemm_bnrelu(const float* __restrict__ G, Ptrs4 Wp, Ptrs4 bp, Ptrs4 gbp,
                 const float* __restrict__ bns, const float* __restrict__ bnq,
                 float* __restrict__ Xout, float* __restrict__ accb, int first)
{
    const int b = blockIdx.z;
    const float* Wb = sel(Wp, b);
    const float* bb = sel(bp, b);
    const float* gb = sel(gbp, b);
    const float* Gb = G + (size_t)b * NN * DD;
    float* O = Xout + (size_t)b * NN * DD;
    float* Ab = accb + (size_t)b * NN * DD;
    const int row0 = blockIdx.y * 128, col0 = blockIdx.x * 64;
    const int tid = threadIdx.x;
    __shared__ float Asm[16][132];
    __shared__ float Bsm[16][68];
    __shared__ float scs[DD], shs[DD];
    {
        float mu = bns[b * DD + tid] * (1.0f / NN);
        float ms = bnq[b * DD + tid] * (1.0f / NN);
        float var = ms - mu * mu;
        float sc = gb[tid] / sqrtf(var + 1e-5f);
        scs[tid] = sc;
        shs[tid] = gb[DD + tid] - mu * sc;
    }
    __syncthreads();
    const int tr = (tid >> 4) << 3, tc = (tid & 15) << 2;
    const int m = tid & 127, kk = (tid >> 7) << 3;
    const int bk = tid >> 4, bn = (tid & 15) << 2;
    const float* aSrc = Gb + (size_t)(row0 + m) * DD + kk;
    const float* bSrc = Wb + (size_t)bk * DD + col0 + bn;

    float acc[8][4] = {};
    float4 pa0 = *(const float4*)(aSrc);
    float4 pa1 = *(const float4*)(aSrc + 4);
    float4 pb  = *(const float4*)(bSrc);
    for (int t = 0; t < DD / 16; ++t) {
        {
            const int kg = t * 16 + kk;
            float vv[8] = {pa0.x, pa0.y, pa0.z, pa0.w, pa1.x, pa1.y, pa1.z, pa1.w};
            #pragma unroll
            for (int i = 0; i < 8; ++i) {
                float v = fmaf(vv[i], scs[kg + i], shs[kg + i]);
                Asm[kk + i][m] = v > 0.f ? v : 0.f;
            }
            *(float4*)&Bsm[bk][bn] = pb;
        }
        __syncthreads();
        if (t < DD / 16 - 1) {
            const int k0 = (t + 1) * 16;
            pa0 = *(const float4*)(aSrc + k0);
            pa1 = *(const float4*)(aSrc + k0 + 4);
            pb  = *(const float4*)(bSrc + (size_t)k0 * DD);
        }
        #pragma unroll
        for (int k = 0; k < 16; ++k) {
            float a[8], bv[4];
            *(float4*)&a[0] = *(const float4*)&Asm[k][tr];
            *(float4*)&a[4] = *(const float4*)&Asm[k][tr + 4];
            *(float4*)&bv[0] = *(const float4*)&Bsm[k][tc];
            #pragma unroll
            for (int i = 0; i < 8; ++i)
                #pragma unroll
                for (int j = 0; j < 4; ++j)
                    acc[i][j] = fmaf(a[i], bv[j], acc[i][j]);
        }
        __syncthreads();
    }
    float bias4[4];
    *(float4*)bias4 = *(const float4*)(bb + col0 + tc);
    #pragma unroll
    for (int i = 0; i < 8; ++i) {
        size_t idx = (size_t)(row0 + tr + i) * DD + col0 + tc;
        float4 o;
        o.x = acc[i][0] + bias4[0]; o.y = acc[i][1] + bias4[1];
        o.z = acc[i][2] + bias4[2]; o.w = acc[i][3] + bias4[3];
        *(float4*)(O + idx) = o;
        if (first) {
            *(float4*)(Ab + idx) = o;
        } else {
            float4 p = *(const float4*)(Ab + idx);
            p.x += o.x; p.y += o.y; p.z += o.z; p.w += o.w;
            *(float4*)(Ab + idx) = p;
        }
    }
}

__global__ __launch_bounds__(256)
void mse_partial(const float* __restrict__ accb, double* __restrict__ msep)
{
    const int pair = blockIdx.x;
    const float* A_ = accb + (size_t)pair * NN * DD;
    const float* B_ = accb + (size_t)3 * NN * DD;
    const size_t total = (size_t)NN * DD;
    double s = 0.0;
    for (size_t i = (size_t)blockIdx.y * blockDim.x + threadIdx.x; i < total;
         i += (size_t)gridDim.y * blockDim.x) {
        float d = A_[i] - B_[i];
        s += (double)d * (double)d;
    }
    __shared__ double red[256];
    red[threadIdx.x] = s;
    __syncthreads();
    for (int st = 128; st > 0; st >>= 1) {
        if (threadIdx.x < st) red[threadIdx.x] += red[threadIdx.x + st];
        __syncthreads();
    }
    if (threadIdx.x == 0) atomicAdd(&msep[pair], red[0]);
}

__global__ void mse_final(const double* __restrict__ msep, float* __restrict__ out)
{
    int i = threadIdx.x;
    if (i < 3) out[i] = (float)(msep[i] / ((double)NN * DD) / 9.0);
}

static inline Ptrs4 mk4(const float* a, const float* b, const float* c, const float* d) {
    Ptrs4 p; p.p0 = a; p.p1 = b; p.p2 = c; p.p3 = d; return p;
}
static inline Ptrs4U mk4u(const ushort_t* a, const ushort_t* b, const ushort_t* c, const ushort_t* d) {
    Ptrs4U p; p.p0 = a; p.p1 = b; p.p2 = c; p.p3 = d; return p;
}

extern "C" void kernel_launch(void* const* d_in, const int* in_sizes, int n_in,
                              void* d_out, int out_size, void* d_ws, size_t ws_size,
                              hipStream_t stream)
{
    (void)in_sizes; (void)n_in; (void)out_size;
    const float* adjW[3]  = {(const float*)d_in[4],  (const float*)d_in[9],  (const float*)d_in[14]};
    const float* adjb[3]  = {(const float*)d_in[5],  (const float*)d_in[10], (const float*)d_in[15]};
    const float* mlpW[3]  = {(const float*)d_in[6],  (const float*)d_in[11], (const float*)d_in[16]};
    const float* mlpb[3]  = {(const float*)d_in[7],  (const float*)d_in[12], (const float*)d_in[17]};
    const float* mlpbn[3] = {(const float*)d_in[8],  (const float*)d_in[13], (const float*)d_in[18]};

    char* ws = (char*)d_ws;
    double* msep  = (double*)ws;                 // [3]
    float* colsum = (float*)(ws + 64);           // [3][4][256]
    float* bnsum  = colsum + 3 * 4 * DD;
    float* bnsq   = bnsum  + 3 * 4 * DD;
    float* tvals  = bnsq   + 3 * 4 * DD;         // [4]
    const size_t tensN = (size_t)4 * NN * DD;
    const size_t HS_BYTES = (size_t)4 * 3 * DD * NN * 2;   // 25.17 MB
    const size_t MASK_BYTES = (size_t)4 * NN * (NN / 8);   // 8.39 MB
    const size_t WSP_BYTES = (size_t)24 * 3 * DD * DD * 2; // 9.44 MB

    float* Xbuf = (float*)(ws + 65536);
    float* Abuf = Xbuf + tensN;

    const size_t need_fast = 65536 + 2 * tensN * 4 + HS_BYTES + tensN * 4 + MASK_BYTES;
    const bool fast  = ws_size >= need_fast;
    const bool fast2 = ws_size >= need_fast + WSP_BYTES;

    float* Bbuf = nullptr; float* accb; uint8_t* mask;
    ushort_t *Sh, *Sm, *Sl, *HsG = nullptr, *Wsp = nullptr;
    if (fast) {
        char* hr = (char*)(Abuf + tensN);
        HsG  = (ushort_t*)hr;
        Sl   = (ushort_t*)hr;
        accb = (float*)(hr + HS_BYTES);
        mask = (uint8_t*)(accb + tensN);
        Wsp  = (ushort_t*)(mask + MASK_BYTES);
    } else {
        Bbuf = Abuf + tensN;
        accb = Bbuf + tensN;
        mask = (uint8_t*)(accb + tensN);
        Sl   = (ushort_t*)Bbuf;
    }
    Sh = (ushort_t*)Abuf;
    Sm = Sh + tensN;

    hipMemsetAsync(ws, 0, 64 + 3 * 3 * 4 * DD * sizeof(float), stream);
    for (int b = 0; b < 4; ++b)
        hipMemcpyAsync(Xbuf + (size_t)b * NN * DD, d_in[b], (size_t)NN * DD * sizeof(float),
                       hipMemcpyDeviceToDevice, stream);

    dim3 gS(4, 32, 4);      // GEMMs / masked_mfma (64-col tiles)
    dim3 gA(528, 1, 4);     // adj tiles, compact upper-tri
    dim3 gT(64, 4, 4);      // tsplit_x
    dim3 blk(256);

    if (fast2) {
        PtrsW wp; wp.a0 = adjW[0]; wp.a1 = adjW[1]; wp.a2 = adjW[2];
                  wp.m0 = mlpW[0]; wp.m1 = mlpW[1]; wp.m2 = mlpW[2];
        wsplitk<<<dim3(4, 4, 24), blk, 0, stream>>>(wp, Wsp);
    }
    const size_t MATB = (size_t)3 * DD * DD;   // ushorts per matrix
    #define WMATA(s)    (Wsp + (size_t)0 * MATB)   // placeholder
    for (int l = 0; l < NL; ++l) {
        float* cs_l = colsum + l * 4 * DD;
        float* bs_l = bnsum + l * 4 * DD;
        float* bq_l = bnsq  + l * 4 * DD;
        #define MK(arr, off) mk4(arr[0] + (off), arr[1] + (off), arr[2] + (off), arr[1] + (off))
        #define MKW(expr0, expr1, expr2) mk4u(Wsp + (expr0) * MATB, Wsp + (expr1) * MATB, \
                                              Wsp + (expr2) * MATB, Wsp + (expr1) * MATB)
        if (fast2) {
            // h1 = elu(X @ aW0 + ab0) : mats z = br*2+0
            gemm_mfma<0><<<gS, blk, 0, stream>>>(Xbuf, MKW(0, 2, 4), MK(adjb, 0),
                                                 Abuf, nullptr, nullptr);
        } else {
            gemm_small<0><<<gS, blk, 0, stream>>>(Xbuf, MK(adjW, 0), MK(adjb, 0), Abuf,
                                                  nullptr, nullptr, (ushort_t*)nullptr);
        }
        if (fast) {
            gemm_small<3><<<gS, blk, 0, stream>>>(Abuf, MK(adjW, (size_t)DD * DD), MK(adjb, DD),
                                                  nullptr, cs_l, nullptr, HsG);
            thresh_k<<<4, blk, 0, stream>>>(cs_l, tvals);
            adj_mfma_v2<<<gA, blk, 0, stream>>>(HsG, tvals, mask);
        } else {
            gemm_small<1><<<gS, blk, 0, stream>>>(Abuf, MK(adjW, (size_t)DD * DD), MK(adjb, DD),
                                                  Bbuf, cs_l, nullptr, (ushort_t*)nullptr);
            thresh_k<<<4, blk, 0, stream>>>(cs_l, tvals);
            adj_mfma_s<<<gA, blk, 0, stream>>>(Bbuf, tvals, mask);
        }
        tsplit_x<<<gT, blk, 0, stream>>>(Xbuf, Sh, Sm, Sl);
        masked_mfma<<<gS, blk, 0, stream>>>(Xbuf, Sh, Sm, Sl, mask);
        const size_t w0 = (size_t)l * 2 * DD * DD, b0 = (size_t)l * 2 * DD;
        if (fast2) {
            // g = X' @ mW0 + mb0 + BN stats : mats z = 6 + br*6 + l*2 + 0
            gemm_mfma<2><<<gS, blk, 0, stream>>>(Xbuf,
                MKW(6 + 0 * 6 + l * 2, 6 + 1 * 6 + l * 2, 6 + 2 * 6 + l * 2),
                MK(mlpb, b0), Abuf, bs_l, bq_l);
            // X = relu(bn(g)) @ mW1 + mb1 : mats z = 6 + br*6 + l*2 + 1
            gemm_bnrelu_m<<<gS, blk, 0, stream>>>(Abuf,
                MKW(6 + 0 * 6 + l * 2 + 1, 6 + 1 * 6 + l * 2 + 1, 6 + 2 * 6 + l * 2 + 1),
                MK(mlpb, b0 + DD), MK(mlpbn, b0), bs_l, bq_l, Xbuf, accb, (l == 0) ? 1 : 0);
        } else {
            gemm_small<2><<<gS, blk, 0, stream>>>(Xbuf, MK(mlpW, w0), MK(mlpb, b0), Abuf,
                                                  bs_l, bq_l, (ushort_t*)nullptr);
            gemm_bnrelu<<<gS, blk, 0, stream>>>(Abuf, MK(mlpW, w0 + (size_t)DD * DD),
                                                MK(mlpb, b0 + DD), MK(mlpbn, b0),
                                                bs_l, bq_l, Xbuf, accb, (l == 0) ? 1 : 0);
        }
        #undef MKW
        #undef MK
    }
    mse_partial<<<dim3(3, 64), blk, 0, stream>>>(accb, msep);
    mse_final<<<1, 64, 0, stream>>>(msep, (float*)d_out);
}